// Round 1
// baseline (3191.118 us; speedup 1.0000x reference)
//
#include <hip/hip_runtime.h>
#include <hip/hip_bf16.h>

#define B_   8
#define N_   1024
#define TD_  5120
#define SD_  2048
#define BD_  1024
#define K_   16
#define M_   4
#define H_   8
#define HD_  256

typedef unsigned short u16;
typedef __attribute__((ext_vector_type(8))) short bf16x8;
typedef __attribute__((ext_vector_type(4))) float f32x4;
typedef __attribute__((ext_vector_type(8))) u16 u16x8;

__device__ __forceinline__ float bf2f(u16 u) {
    union { unsigned int i; float f; } x; x.i = ((unsigned)u) << 16; return x.f;
}
__device__ __forceinline__ u16 f2bf(float f) {
    union { float f; unsigned int i; } x; x.f = f;
    unsigned int i = x.i;
    return (u16)((i + 0x7fffu + ((i >> 16) & 1u)) >> 16);
}
__device__ __forceinline__ float gelu_exact(float v) {
    return 0.5f * v * (1.0f + erff(v * 0.70710678118654752f));
}

__device__ __forceinline__ void gload_lds16(const void* g, void* l) {
    __builtin_amdgcn_global_load_lds(
        (const __attribute__((address_space(1))) unsigned int*)g,
        (__attribute__((address_space(3))) unsigned int*)l, 16, 0, 0);
}

// ---------------- GEMM: C(M,N) = epi(A(M,K) @ Bt(N,K)^T + bias) ----------------
// 128x128 tile, BK=32, 4 waves (2x2, 64x64 each), mfma_f32_16x16x32_bf16.
template<int EPI, typename TO>   // EPI: 0 = bias, 1 = bias+gelu ; TO: u16(bf16) or float
__global__ __launch_bounds__(256, 2)
void gemm_bt(const u16* __restrict__ A, int lda,
             const u16* __restrict__ Bt, int ldb,
             const float* __restrict__ bias,
             TO* __restrict__ C, int ldc, int Kd)
{
    __shared__ u16 As[128][32];
    __shared__ u16 Bs[128][32];
    const int tid  = threadIdx.x;
    const int wave = tid >> 6, lane = tid & 63;
    const int row0 = blockIdx.x * 128, col0 = blockIdx.y * 128;
    const int wr = wave >> 1, wc = wave & 1;
    f32x4 acc[4][4] = {};
    const int srow  = tid >> 2;
    const int scolb = (tid & 3) << 4;
    const char* aP0 = (const char*)(A  + (size_t)(row0 + srow)      * lda) + scolb;
    const char* aP1 = (const char*)(A  + (size_t)(row0 + 64 + srow) * lda) + scolb;
    const char* bP0 = (const char*)(Bt + (size_t)(col0 + srow)      * ldb) + scolb;
    const char* bP1 = (const char*)(Bt + (size_t)(col0 + 64 + srow) * ldb) + scolb;
    char* asW = (char*)&As[0][0] + wave * 1024;
    char* bsW = (char*)&Bs[0][0] + wave * 1024;
    const int fr = lane & 15, fk = (lane >> 4) << 3;
    const int nkt = Kd >> 5;
    for (int kt = 0; kt < nkt; ++kt) {
        const int kb = kt << 6;   // kt*32 elems * 2B
        __syncthreads();
        gload_lds16(aP0 + kb, asW);
        gload_lds16(aP1 + kb, asW + 4096);
        gload_lds16(bP0 + kb, bsW);
        gload_lds16(bP1 + kb, bsW + 4096);
        asm volatile("s_waitcnt vmcnt(0)" ::: "memory");
        __syncthreads();
        bf16x8 af[4], bfr[4];
#pragma unroll
        for (int m = 0; m < 4; ++m) af[m]  = *(const bf16x8*)&As[wr*64 + m*16 + fr][fk];
#pragma unroll
        for (int n = 0; n < 4; ++n) bfr[n] = *(const bf16x8*)&Bs[wc*64 + n*16 + fr][fk];
#pragma unroll
        for (int m = 0; m < 4; ++m)
#pragma unroll
            for (int n = 0; n < 4; ++n)
                acc[m][n] = __builtin_amdgcn_mfma_f32_16x16x32_bf16(af[m], bfr[n], acc[m][n], 0, 0, 0);
    }
    const int fq = lane >> 4;
#pragma unroll
    for (int m = 0; m < 4; ++m)
#pragma unroll
        for (int n = 0; n < 4; ++n) {
            const int col = col0 + wc*64 + n*16 + fr;
            const float bv = bias[col];
#pragma unroll
            for (int j = 0; j < 4; ++j) {
                const int row = row0 + wr*64 + m*16 + fq*4 + j;
                float v = acc[m][n][j] + bv;
                if (EPI == 1) v = gelu_exact(v);
                if constexpr (sizeof(TO) == 2) C[(size_t)row*ldc + col] = f2bf(v);
                else                           C[(size_t)row*ldc + col] = v;
            }
        }
}

// ---------------- conversions ----------------
__global__ void cvt_bf16_flat(const float* __restrict__ in, u16* __restrict__ out, long n8) {
    long i = (long)blockIdx.x * blockDim.x + threadIdx.x;
    const long stride = (long)gridDim.x * blockDim.x;
    for (; i < n8; i += stride) {
        const f32x4* p = (const f32x4*)in + i*2;
        f32x4 a = p[0], b = p[1];
        u16x8 o;
        o[0]=f2bf(a[0]); o[1]=f2bf(a[1]); o[2]=f2bf(a[2]); o[3]=f2bf(a[3]);
        o[4]=f2bf(b[0]); o[5]=f2bf(b[1]); o[6]=f2bf(b[2]); o[7]=f2bf(b[3]);
        ((u16x8*)out)[i] = o;
    }
}

// W (Kdim,Ndim) f32 -> Wt (Ndim,Kdim) bf16
__global__ void cvt_transpose(const float* __restrict__ W, u16* __restrict__ Wt, int Kdim, int Ndim) {
    __shared__ float t[32][33];
    const int k0 = blockIdx.x * 32, n0 = blockIdx.y * 32;
    const int c = threadIdx.x & 31, rg = threadIdx.x >> 5;
#pragma unroll
    for (int j = 0; j < 4; ++j) {
        int r = rg*4 + j;
        t[r][c] = W[(size_t)(k0 + r)*Ndim + n0 + c];
    }
    __syncthreads();
#pragma unroll
    for (int j = 0; j < 4; ++j) {
        int r = rg*4 + j;
        Wt[(size_t)(n0 + r)*Kdim + k0 + c] = f2bf(t[c][r]);
    }
}

// ---------------- LayerNorm (bf16 in -> bf16 out), row length SD_ ----------------
__global__ __launch_bounds__(256)
void ln_rows(const u16* __restrict__ in, u16* __restrict__ out,
             const float* __restrict__ g, const float* __restrict__ bt) {
    const int row = blockIdx.x, tid = threadIdx.x;
    const u16x8 v = ((const u16x8*)(in + (size_t)row*SD_))[tid];
    float f[8]; float s = 0.f, s2 = 0.f;
#pragma unroll
    for (int j = 0; j < 8; ++j) { f[j] = bf2f(v[j]); s += f[j]; s2 += f[j]*f[j]; }
    __shared__ float sa[4], sb[4];
#pragma unroll
    for (int o = 32; o > 0; o >>= 1) { s += __shfl_down(s, o); s2 += __shfl_down(s2, o); }
    if ((tid & 63) == 0) { sa[tid >> 6] = s; sb[tid >> 6] = s2; }
    __syncthreads();
    s = sa[0]+sa[1]+sa[2]+sa[3]; s2 = sb[0]+sb[1]+sb[2]+sb[3];
    const float mean = s * (1.0f/SD_);
    const float var  = s2 * (1.0f/SD_) - mean*mean;
    const float inv  = rsqrtf(var + 1e-5f);
    const int c0 = tid*8;
    u16x8 o;
#pragma unroll
    for (int j = 0; j < 8; ++j) o[j] = f2bf((f[j]-mean)*inv*g[c0+j] + bt[c0+j]);
    ((u16x8*)(out + (size_t)row*SD_))[tid] = o;
}

// ---------------- final LN: LN(ctx2 + q[k], pg, pb) -> f32 out ----------------
__global__ __launch_bounds__(256)
void ln_post(const float* __restrict__ ctx2, const float* __restrict__ q,
             const float* __restrict__ g, const float* __restrict__ bt,
             float* __restrict__ outb, int ob_stride) {
    const int rowi = blockIdx.x, tid = threadIdx.x;
    const int b = rowi >> 4, k = rowi & 15;
    const float* ip = ctx2 + (size_t)rowi*SD_;
    const float* qr = q + (size_t)k*SD_;
    float f[8]; float s = 0.f, s2 = 0.f;
#pragma unroll
    for (int j = 0; j < 8; ++j) {
        const int c = tid + j*256;
        f[j] = ip[c] + qr[c];
        s += f[j]; s2 += f[j]*f[j];
    }
    __shared__ float sa[4], sb[4];
#pragma unroll
    for (int o = 32; o > 0; o >>= 1) { s += __shfl_down(s, o); s2 += __shfl_down(s2, o); }
    if ((tid & 63) == 0) { sa[tid >> 6] = s; sb[tid >> 6] = s2; }
    __syncthreads();
    s = sa[0]+sa[1]+sa[2]+sa[3]; s2 = sb[0]+sb[1]+sb[2]+sb[3];
    const float mean = s * (1.0f/SD_);
    const float inv  = rsqrtf(s2 * (1.0f/SD_) - mean*mean + 1e-5f);
    float* op = outb + (size_t)b*ob_stride + (size_t)k*SD_;
#pragma unroll
    for (int j = 0; j < 8; ++j) { const int c = tid + j*256; op[c] = (f[j]-mean)*inv*g[c] + bt[c]; }
}

// ---------------- q-projection for all 5 adapters ----------------
struct Ptr5 { const float* p[5]; };

__global__ __launch_bounds__(256)
void qp_all_k(Ptr5 q, Ptr5 wq, Ptr5 bq, float* __restrict__ qp) {
    const int a = blockIdx.y;
    const int c = blockIdx.x * 256 + threadIdx.x;
    const float* Q = q.p[a]; const float* W = wq.p[a];
    float acc[16];
    const float bv = bq.p[a][c];
#pragma unroll
    for (int k = 0; k < 16; ++k) acc[k] = bv;
    for (int i = 0; i < SD_; ++i) {
        const float w = W[(size_t)i*SD_ + c];
#pragma unroll
        for (int k = 0; k < 16; ++k) acc[k] += Q[k*SD_ + i] * w;
    }
#pragma unroll
    for (int k = 0; k < 16; ++k) qp[((size_t)a*16 + k)*SD_ + c] = acc[k];
}

// ---------------- attention ----------------
// partial scores: grid (4 nchunk, 64 bh, 4 dchunk)
__global__ __launch_bounds__(256)
void scores_part(const u16* __restrict__ kv, const float* __restrict__ qp, float* __restrict__ Sp) {
    const int nc = blockIdx.x, bh = blockIdx.y, dc = blockIdx.z;
    const int b = bh >> 3, h = bh & 7;
    const int n = nc*256 + threadIdx.x;
    const u16* kr = kv + (size_t)(b*1024 + n)*4096 + h*256 + dc*64;
    const float* qr = qp + h*256 + dc*64;
    float acc[16] = {};
    for (int d0 = 0; d0 < 64; d0 += 8) {
        u16x8 kvv = *(const u16x8*)(kr + d0);
        float vf[8];
#pragma unroll
        for (int j = 0; j < 8; ++j) vf[j] = bf2f(kvv[j]);
#pragma unroll
        for (int k = 0; k < 16; ++k) {
            const float* qq = qr + (size_t)k*SD_ + d0;
#pragma unroll
            for (int j = 0; j < 8; ++j) acc[k] += qq[j] * vf[j];
        }
    }
#pragma unroll
    for (int k = 0; k < 16; ++k)
        Sp[(((size_t)dc*64 + bh)*16 + k)*1024 + n] = acc[k];
}

__global__ void scores_reduce(const float* __restrict__ Sp, float* __restrict__ S) {
    const size_t i = (size_t)blockIdx.x*256 + threadIdx.x;   // over 1,048,576
    const float v = Sp[i] + Sp[i + 1048576] + Sp[i + 2*1048576] + Sp[i + 3*1048576];
    S[i] = v * 0.0625f;
}

// softmax over n (row len 1024), write transposed St[bh][n][k]
__global__ __launch_bounds__(256)
void softmax_t(const float* __restrict__ S, float* __restrict__ St) {
    const int r = blockIdx.x;           // bh*16 + k
    const int bh = r >> 4, k = r & 15;
    const int tid = threadIdx.x;
    const float* row = S + (size_t)r*1024;
    float v[4];
#pragma unroll
    for (int j = 0; j < 4; ++j) v[j] = row[tid + j*256];
    float mx = fmaxf(fmaxf(v[0],v[1]), fmaxf(v[2],v[3]));
    __shared__ float sa[4], sb[4];
#pragma unroll
    for (int o = 1; o < 64; o <<= 1) mx = fmaxf(mx, __shfl_xor(mx, o));
    if ((tid & 63) == 0) sa[tid >> 6] = mx;
    __syncthreads();
    mx = fmaxf(fmaxf(sa[0],sa[1]), fmaxf(sa[2],sa[3]));
    float s = 0.f;
#pragma unroll
    for (int j = 0; j < 4; ++j) { v[j] = expf(v[j]-mx); s += v[j]; }
#pragma unroll
    for (int o = 1; o < 64; o <<= 1) s += __shfl_xor(s, o);
    if ((tid & 63) == 0) sb[tid >> 6] = s;
    __syncthreads();
    s = sb[0]+sb[1]+sb[2]+sb[3];
    const float inv = 1.0f/s;
#pragma unroll
    for (int j = 0; j < 4; ++j)
        St[((size_t)bh*1024 + tid + j*256)*16 + k] = v[j]*inv;
}

// partial PV: grid (4 nchunk, 64 bh), thread = d
__global__ __launch_bounds__(256)
void ctx_part(const u16* __restrict__ kv, const float* __restrict__ St, float* __restrict__ Cp) {
    const int nc = blockIdx.x, bh = blockIdx.y;
    const int b = bh >> 3, h = bh & 7;
    const int d = threadIdx.x;
    const u16* vcol = kv + (size_t)(b*1024 + nc*256)*4096 + 2048 + h*256 + d;
    const float* sr = St + ((size_t)bh*1024 + nc*256)*16;
    float acc[16] = {};
    for (int n = 0; n < 256; ++n) {
        const float vv = bf2f(vcol[(size_t)n*4096]);
        const float* srn = sr + n*16;
#pragma unroll
        for (int k = 0; k < 16; ++k) acc[k] += srn[k] * vv;
    }
#pragma unroll
    for (int k = 0; k < 16; ++k)
        Cp[(((size_t)nc*8 + b)*16 + k)*2048 + h*256 + d] = acc[k];
}

__global__ void ctx_reduce(const float* __restrict__ Cp, u16* __restrict__ ctxb) {
    const size_t i = (size_t)blockIdx.x*256 + threadIdx.x;   // over 262,144
    const float v = Cp[i] + Cp[i + 262144] + Cp[i + 2*262144] + Cp[i + 3*262144];
    ctxb[i] = f2bf(v);
}

// ---------------- router ----------------
__global__ void pool_mean(const float* __restrict__ h, float* __restrict__ pooled) {
    const int c = blockIdx.x*256 + threadIdx.x;
    const int b = blockIdx.y;
    const float* p = h + (size_t)b*N_*TD_ + c;
    float s = 0.f;
    for (int n = 0; n < N_; ++n) s += p[(size_t)n*TD_];
    pooled[b*TD_ + c] = s * (1.0f/N_);
}

__global__ void router_mlp1(const float* __restrict__ pooled, const float* __restrict__ w1,
                            const float* __restrict__ b1, float* __restrict__ hid) {
    const int c = blockIdx.x*256 + threadIdx.x;   // 0..511
    const int b = blockIdx.y;
    const float* pr = pooled + b*TD_;
    float s = b1[c];
    for (int i = 0; i < TD_; ++i) s += pr[i] * w1[(size_t)i*512 + c];
    hid[b*512 + c] = gelu_exact(s);
}

__global__ void router_final(const float* __restrict__ hid, const float* __restrict__ w2,
                             const float* __restrict__ b2, float* __restrict__ probs,
                             int* __restrict__ widx, float* __restrict__ wval) {
    __shared__ float lg[8][4];
    const int tid = threadIdx.x;
    if (tid < 32) {
        const int b = tid >> 2, m = tid & 3;
        float s = b2[m];
        const float* hr = hid + b*512;
        for (int i = 0; i < 512; ++i) s += hr[i]*w2[i*4 + m];
        lg[b][m] = s;
    }
    __syncthreads();
    if (tid < 8) {
        const int b = tid;
        const float l0=lg[b][0], l1=lg[b][1], l2=lg[b][2], l3=lg[b][3];
        const float mx = fmaxf(fmaxf(l0,l1),fmaxf(l2,l3));
        const float e0=expf(l0-mx), e1=expf(l1-mx), e2=expf(l2-mx), e3=expf(l3-mx);
        const float s = e0+e1+e2+e3;
        float p[4] = {e0/s, e1/s, e2/s, e3/s};
        probs[b*4+0]=p[0]; probs[b*4+1]=p[1]; probs[b*4+2]=p[2]; probs[b*4+3]=p[3];
        int i0 = 0;
        for (int m = 1; m < 4; ++m) if (p[m] > p[i0]) i0 = m;
        int i1 = -1;
        for (int m = 0; m < 4; ++m) if (m != i0 && (i1 < 0 || p[m] > p[i1])) i1 = m;
        const float w0 = p[i0], w1 = p[i1], ws = w0 + w1 + 1e-8f;
        widx[b*2]=i0; widx[b*2+1]=i1;
        wval[b*2]=w0/ws; wval[b*2+1]=w1/ws;
    }
}

__global__ void combine_k(const float* __restrict__ cspec, const int* __restrict__ widx,
                          const float* __restrict__ wval, float* __restrict__ out) {
    const int i = blockIdx.x*256 + threadIdx.x;   // 65536 float4s
    const int c4 = i & 511;
    const int bk = i >> 9;                        // 0..127
    const int b = bk >> 4, k = bk & 15;
    const int i0 = widx[b*2], i1 = widx[b*2+1];
    const float w0 = wval[b*2], w1 = wval[b*2+1];
    const f32x4 v0 = ((const f32x4*)(cspec + (size_t)i0*262144))[bk*512 + c4];
    const f32x4 v1 = ((const f32x4*)(cspec + (size_t)i1*262144))[bk*512 + c4];
    ((f32x4*)out)[(size_t)(b*32 + 16 + k)*512 + c4] = v0*w0 + v1*w1;
}

// ---------------- pack helpers ----------------
__global__ void pack_bias5(Ptr5 bs, float* __restrict__ dst) {
    const int i = blockIdx.x*256 + threadIdx.x;   // 5120
    dst[i] = bs.p[i >> 10][i & 1023];
}
__global__ void copy2(const float* __restrict__ a, const float* __restrict__ b, float* __restrict__ dst) {
    const int i = blockIdx.x*256 + threadIdx.x;   // 4096
    dst[i] = (i < 2048) ? a[i] : b[i - 2048];
}

// ---------------- host ----------------
extern "C" void kernel_launch(void* const* d_in, const int* in_sizes, int n_in,
                              void* d_out, int out_size, void* d_ws, size_t ws_size,
                              hipStream_t stream) {
    if (ws_size < 300300000ULL) return;   // workspace plan needs ~286 MiB

    const float* h = (const float*)d_in[0];
    const float* G[17]; const float* Sx[17];
    for (int i = 0; i < 17; ++i) { G[i] = (const float*)d_in[1+i]; Sx[i] = (const float*)d_in[18+i]; }
    const float* r_w1 = (const float*)d_in[35];
    const float* r_b1 = (const float*)d_in[36];
    const float* r_w2 = (const float*)d_in[37];
    const float* r_b2 = (const float*)d_in[38];

    static const size_t str[17] = {
        (size_t)TD_*BD_, BD_, (size_t)BD_*SD_, SD_, SD_, SD_, (size_t)K_*SD_,
        (size_t)SD_*SD_, (size_t)SD_*SD_, (size_t)SD_*SD_, (size_t)SD_*SD_,
        SD_, SD_, SD_, SD_, SD_, SD_ };
    auto P = [&](int pi, int a) -> const float* {
        return (a == 0) ? G[pi] : Sx[pi] + (size_t)(a-1)*str[pi];
    };

    char* w = (char*)d_ws;
    u16*   h_bf   = (u16*)(w + 0);             // 83,886,080 (dead after GEMM1)
    u16*   ybuf   = (u16*)(w + 0);             // alias, 33,554,432
    u16*   xbuf   = (u16*)(w + 41943040);      // 33,554,432
    u16*   x1_all = (u16*)(w + 83886080);      // 83,886,080
    u16*   wt_dw  = (u16*)(w + 167772160);     // 52,428,800 (dead after GEMM1)
    u16*   kv     = (u16*)(w + 167772160);     // alias, 67,108,864
    u16*   wt_uw  = (u16*)(w + 234881024);     // 4,194,304
    u16*   wt_kv  = (u16*)(w + 239075328);     // 16,777,216
    u16*   wt_ow  = (u16*)(w + 255852544);     // 8,388,608
    float* qp_all = (float*)(w + 264241152);   // 655,360
    float* Sp     = (float*)(w + 264896512);   // 16,777,216
    float* Sbuf   = (float*)(w + 281673728);   // 4,194,304
    float* St     = (float*)(w + 285868032);   // 4,194,304
    float* Cp     = (float*)(w + 290062336);   // 4,194,304
    u16*   ctxb   = (u16*)(w + 294256640);     // 524,288
    float* ctx2   = (float*)(w + 294780928);   // 1,048,576
    float* cspec  = (float*)(w + 295829504);   // 4,194,304
    float* bias5  = (float*)(w + 300023808);   // 20,480
    float* biaskv = (float*)(w + 300044288);   // 16,384
    float* pooled = (float*)(w + 300060672);   // 163,840
    float* hid    = (float*)(w + 300224512);   // 16,384
    int*   widx   = (int*)  (w + 300240896);   // 64
    float* wval   = (float*)(w + 300240960);   // 64

    float* out = (float*)d_out;

    // h -> bf16 ; router path
    cvt_bf16_flat<<<2048, 256, 0, stream>>>(h, h_bf, (long)((size_t)B_*N_*TD_/8));
    pool_mean<<<dim3(20, 8), 256, 0, stream>>>(h, pooled);
    router_mlp1<<<dim3(2, 8), 256, 0, stream>>>(pooled, r_w1, r_b1, hid);
    router_final<<<1, 64, 0, stream>>>(hid, r_w2, r_b2, out + 524288, widx, wval);

    // q-projections for all adapters
    Ptr5 q5, wq5, bq5, db5;
    for (int a = 0; a < 5; ++a) { q5.p[a] = P(6,a); wq5.p[a] = P(7,a); bq5.p[a] = P(11,a); db5.p[a] = P(1,a); }
    qp_all_k<<<dim3(8, 5), 256, 0, stream>>>(q5, wq5, bq5, qp_all);

    // batched down-projection over all 5 adapters
    for (int a = 0; a < 5; ++a)
        cvt_transpose<<<dim3(TD_/32, BD_/32), 256, 0, stream>>>(P(0,a), wt_dw + (size_t)a*BD_*TD_, TD_, BD_);
    pack_bias5<<<20, 256, 0, stream>>>(db5, bias5);
    gemm_bt<1, u16><<<dim3(64, 40), 256, 0, stream>>>(h_bf, TD_, wt_dw, TD_, bias5, x1_all, 5*BD_, TD_);

    for (int a = 0; a < 5; ++a) {
        // up-projection + LN
        cvt_transpose<<<dim3(BD_/32, SD_/32), 256, 0, stream>>>(P(2,a), wt_uw, BD_, SD_);
        gemm_bt<0, u16><<<dim3(64, 16), 256, 0, stream>>>(x1_all + (size_t)a*BD_, 5*BD_, wt_uw, BD_, P(3,a), ybuf, SD_, BD_);
        ln_rows<<<8192, 256, 0, stream>>>(ybuf, xbuf, P(4,a), P(5,a));
        // K|V projection (packed)
        cvt_transpose<<<dim3(SD_/32, SD_/32), 256, 0, stream>>>(P(8,a), wt_kv, SD_, SD_);
        cvt_transpose<<<dim3(SD_/32, SD_/32), 256, 0, stream>>>(P(9,a), wt_kv + (size_t)SD_*SD_, SD_, SD_);
        copy2<<<16, 256, 0, stream>>>(P(12,a), P(13,a), biaskv);
        gemm_bt<0, u16><<<dim3(64, 32), 256, 0, stream>>>(xbuf, SD_, wt_kv, SD_, biaskv, kv, 2*SD_, SD_);
        // attention
        scores_part<<<dim3(4, 64, 4), 256, 0, stream>>>(kv, qp_all + (size_t)a*16*SD_, Sp);
        scores_reduce<<<4096, 256, 0, stream>>>(Sp, Sbuf);
        softmax_t<<<1024, 256, 0, stream>>>(Sbuf, St);
        ctx_part<<<dim3(4, 64), 256, 0, stream>>>(kv, St, Cp);
        ctx_reduce<<<1024, 256, 0, stream>>>(Cp, ctxb);
        // output projection + residual LN
        cvt_transpose<<<dim3(SD_/32, SD_/32), 256, 0, stream>>>(P(10,a), wt_ow, SD_, SD_);
        gemm_bt<0, float><<<dim3(1, 16), 256, 0, stream>>>(ctxb, SD_, wt_ow, SD_, P(14,a), ctx2, SD_, SD_);
        if (a == 0)
            ln_post<<<128, 256, 0, stream>>>(ctx2, P(6,0), P(15,0), P(16,0), out, 32*SD_);
        else
            ln_post<<<128, 256, 0, stream>>>(ctx2, P(6,a), P(15,a), P(16,a), cspec + (size_t)(a-1)*128*SD_, 16*SD_);
    }
    combine_k<<<256, 256, 0, stream>>>(cspec, widx, wval, out);
}

// Round 2
// 2318.480 us; speedup vs baseline: 1.3764x; 1.3764x over previous
//
#include <hip/hip_runtime.h>
#include <hip/hip_bf16.h>

#define B_   8
#define N_   1024
#define TD_  5120
#define SD_  2048
#define BD_  1024
#define K_   16
#define H_   8

typedef unsigned short u16;
typedef __attribute__((ext_vector_type(8))) short bf16x8;
typedef __attribute__((ext_vector_type(4))) float f32x4;
typedef __attribute__((ext_vector_type(8))) u16 u16x8;

__device__ __forceinline__ float bf2f(u16 u) {
    union { unsigned int i; float f; } x; x.i = ((unsigned)u) << 16; return x.f;
}
__device__ __forceinline__ u16 f2bf(float f) {
    union { float f; unsigned int i; } x; x.f = f;
    unsigned int i = x.i;
    return (u16)((i + 0x7fffu + ((i >> 16) & 1u)) >> 16);
}
__device__ __forceinline__ float gelu_exact(float v) {
    return 0.5f * v * (1.0f + erff(v * 0.70710678118654752f));
}
__device__ __forceinline__ void gload_lds16(const void* g, void* l) {
    __builtin_amdgcn_global_load_lds(
        (const __attribute__((address_space(1))) unsigned int*)g,
        (__attribute__((address_space(3))) unsigned int*)l, 16, 0, 0);
}

struct Ptr5 { const float* p[5]; };
struct Ptr40 { const float* p[8][5]; };

// ============ unit-indexed GEMM: C_u = epi(A_u @ Bt_ua^T + bias_ua) ============
// 128x128 tile, BK=32, double-buffered LDS, chunk-swizzled staging, 4 waves.
// lda == ldb == Kd for all call sites. AMODE 0: A row base = units_b[u]*1024;
// AMODE 1: A row base = u*1024.
template<int EPI, int AMODE>
__global__ __launch_bounds__(256, 2)
void gemm_units(const u16* __restrict__ Abase,
                const u16* __restrict__ Bbase, long bStride,
                const float* __restrict__ biasBase, int biasStride,
                u16* __restrict__ Cbase, int ldc, long cStride,
                int Kd, const int* __restrict__ units_a, const int* __restrict__ units_b)
{
    __shared__ u16 As[2*128*32];
    __shared__ u16 Bs[2*128*32];
    const int u = blockIdx.z;
    const int ua = units_a[u];
    const int ub = (AMODE == 0) ? units_b[u] : u;
    const u16* A  = Abase + (size_t)ub * 1024 * Kd;
    const u16* Bt = Bbase + (size_t)ua * bStride;
    const float* bias = biasBase + (size_t)ua * biasStride;
    u16* C = Cbase + (size_t)u * cStride;

    const int tid  = threadIdx.x;
    const int wave = tid >> 6, lane = tid & 63;
    const int row0 = blockIdx.x * 128, col0 = blockIdx.y * 128;
    const int wr = wave >> 1, wc = wave & 1;

    // staging source (swizzled chunk)
    const int sr  = tid >> 2;                 // local row 0..63
    const int cg  = (tid & 3) ^ ((sr >> 1) & 3);
    const char* aP0 = (const char*)(A  + (size_t)(row0 + sr)      * Kd + cg*8);
    const char* aP1 = (const char*)(A  + (size_t)(row0 + 64 + sr) * Kd + cg*8);
    const char* bP0 = (const char*)(Bt + (size_t)(col0 + sr)      * Kd + cg*8);
    const char* bP1 = (const char*)(Bt + (size_t)(col0 + 64 + sr) * Kd + cg*8);

    // read-side fragment offsets (elements), chunk-swizzled
    const int fr = lane & 15;
    const int chunk = (lane >> 4) ^ ((fr >> 1) & 3);
    int aoff[4], boff[4];
#pragma unroll
    for (int m = 0; m < 4; ++m) aoff[m] = (wr*64 + m*16 + fr)*32 + chunk*8;
#pragma unroll
    for (int n = 0; n < 4; ++n) boff[n] = (wc*64 + n*16 + fr)*32 + chunk*8;

    const int nkt = Kd >> 5;
    // prologue: stage kt=0 into buffer 0
    {
        char* asW = (char*)As + wave*1024;
        char* bsW = (char*)Bs + wave*1024;
        gload_lds16(aP0, asW);
        gload_lds16(aP1, asW + 4096);
        gload_lds16(bP0, bsW);
        gload_lds16(bP1, bsW + 4096);
    }
    asm volatile("s_waitcnt vmcnt(0)" ::: "memory");
    __syncthreads();

    f32x4 acc[4][4] = {};
    int cur = 0;
    for (int kt = 0; kt < nkt; ++kt) {
        if (kt + 1 < nkt) {
            const size_t kb = (size_t)(kt + 1) << 6;   // bytes
            char* asN = (char*)As + (cur^1)*8192 + wave*1024;
            char* bsN = (char*)Bs + (cur^1)*8192 + wave*1024;
            gload_lds16(aP0 + kb, asN);
            gload_lds16(aP1 + kb, asN + 4096);
            gload_lds16(bP0 + kb, bsN);
            gload_lds16(bP1 + kb, bsN + 4096);
        }
        const u16* Ab = As + cur*4096;
        const u16* Bb = Bs + cur*4096;
        bf16x8 af[4], bfr[4];
#pragma unroll
        for (int m = 0; m < 4; ++m) af[m]  = *(const bf16x8*)(Ab + aoff[m]);
#pragma unroll
        for (int n = 0; n < 4; ++n) bfr[n] = *(const bf16x8*)(Bb + boff[n]);
#pragma unroll
        for (int m = 0; m < 4; ++m)
#pragma unroll
            for (int n = 0; n < 4; ++n)
                acc[m][n] = __builtin_amdgcn_mfma_f32_16x16x32_bf16(af[m], bfr[n], acc[m][n], 0, 0, 0);
        asm volatile("s_waitcnt vmcnt(0)" ::: "memory");
        __syncthreads();
        cur ^= 1;
    }

    const int fq = lane >> 4;
#pragma unroll
    for (int m = 0; m < 4; ++m)
#pragma unroll
        for (int n = 0; n < 4; ++n) {
            const int col = col0 + wc*64 + n*16 + fr;
            const float bv = bias[col];
#pragma unroll
            for (int j = 0; j < 4; ++j) {
                const int row = row0 + wr*64 + m*16 + fq*4 + j;
                float v = acc[m][n][j] + bv;
                if (EPI == 1) v = gelu_exact(v);
                C[(size_t)row*ldc + col] = f2bf(v);
            }
        }
}

// ============ conversions ============
__global__ void cvt_bf16_flat(const float* __restrict__ in, u16* __restrict__ out, long n8) {
    long i = (long)blockIdx.x * blockDim.x + threadIdx.x;
    const long stride = (long)gridDim.x * blockDim.x;
    for (; i < n8; i += stride) {
        const f32x4* p = (const f32x4*)in + i*2;
        f32x4 a = p[0], b = p[1];
        u16x8 o;
        o[0]=f2bf(a[0]); o[1]=f2bf(a[1]); o[2]=f2bf(a[2]); o[3]=f2bf(a[3]);
        o[4]=f2bf(b[0]); o[5]=f2bf(b[1]); o[6]=f2bf(b[2]); o[7]=f2bf(b[3]);
        ((u16x8*)out)[i] = o;
    }
}

// W (Kd, Nd) f32 row-major -> Wt (Nd, Kd) bf16 row-major; 64x64 tiles
__global__ __launch_bounds__(256)
void cvt_transpose(const float* __restrict__ W, u16* __restrict__ Wt, int Kd, int Nd) {
    __shared__ float t[64][65];
    const int k0 = blockIdx.x * 64, n0 = blockIdx.y * 64;
    const int tid = threadIdx.x;
#pragma unroll
    for (int i = 0; i < 4; ++i) {
        int ch = tid + i*256;
        int r = ch >> 4, c4 = (ch & 15) << 2;
        f32x4 v = *(const f32x4*)(W + (size_t)(k0 + r)*Nd + n0 + c4);
        t[r][c4] = v[0]; t[r][c4+1] = v[1]; t[r][c4+2] = v[2]; t[r][c4+3] = v[3];
    }
    __syncthreads();
#pragma unroll
    for (int i = 0; i < 2; ++i) {
        int ch = tid + i*256;
        int nr = ch >> 3, c8 = (ch & 7) << 3;
        u16x8 o;
#pragma unroll
        for (int j = 0; j < 8; ++j) o[j] = f2bf(t[c8 + j][nr]);
        *(u16x8*)(Wt + (size_t)(n0 + nr)*Kd + k0 + c8) = o;
    }
}

// ============ LayerNorm in place (bf16), unit-indexed params ============
__global__ __launch_bounds__(256)
void ln_rows_u(u16* __restrict__ X, const float* __restrict__ gslab,
               const float* __restrict__ bslab, const int* __restrict__ units_a) {
    const int row = blockIdx.x, tid = threadIdx.x;
    const int ua = units_a[row >> 10];
    const float* g  = gslab + (size_t)ua*SD_;
    const float* bt = bslab + (size_t)ua*SD_;
    u16* rp = X + (size_t)row*SD_;
    const u16x8 v = ((const u16x8*)rp)[tid];
    float f[8]; float s = 0.f, s2 = 0.f;
#pragma unroll
    for (int j = 0; j < 8; ++j) { f[j] = bf2f(v[j]); s += f[j]; s2 += f[j]*f[j]; }
    __shared__ float sa[4], sb[4];
#pragma unroll
    for (int o = 32; o > 0; o >>= 1) { s += __shfl_down(s, o); s2 += __shfl_down(s2, o); }
    if ((tid & 63) == 0) { sa[tid >> 6] = s; sb[tid >> 6] = s2; }
    __syncthreads();
    s = sa[0]+sa[1]+sa[2]+sa[3]; s2 = sb[0]+sb[1]+sb[2]+sb[3];
    const float mean = s * (1.0f/SD_);
    const float inv  = rsqrtf(s2 * (1.0f/SD_) - mean*mean + 1e-5f);
    const int c0 = tid*8;
    u16x8 o;
#pragma unroll
    for (int j = 0; j < 8; ++j) o[j] = f2bf((f[j]-mean)*inv*g[c0+j] + bt[c0+j]);
    ((u16x8*)rp)[tid] = o;
}

// ============ q-projection for all 5 adapters ============
__global__ __launch_bounds__(256)
void qp_all_k(Ptr5 q, Ptr5 wq, Ptr5 bq, float* __restrict__ qp) {
    const int a = blockIdx.y;
    const int c = blockIdx.x * 256 + threadIdx.x;
    const float* Q = q.p[a]; const float* W = wq.p[a];
    float acc[16];
    const float bv = bq.p[a][c];
#pragma unroll
    for (int k = 0; k < 16; ++k) acc[k] = bv;
    for (int i = 0; i < SD_; ++i) {
        const float w = W[(size_t)i*SD_ + c];
#pragma unroll
        for (int k = 0; k < 16; ++k) acc[k] += Q[k*SD_ + i] * w;
    }
#pragma unroll
    for (int k = 0; k < 16; ++k) qp[((size_t)a*16 + k)*SD_ + c] = acc[k];
}

// ============ fused scores + softmax -> P (f32) ============
// grid: 24*8 blocks (u*8+h), 256 threads
__global__ __launch_bounds__(256)
void scores_sm(const u16* __restrict__ Kb, const float* __restrict__ qp,
               const int* __restrict__ units_a, float* __restrict__ P)
{
    __shared__ float sL[16][1024];
    __shared__ float qL[16][256];
    __shared__ float red[8];
    const int u = blockIdx.x >> 3, hh = blockIdx.x & 7;
    const int ua = units_a[u];
    const int t = threadIdx.x;
    for (int i = t; i < 16*256; i += 256)
        qL[i >> 8][i & 255] = qp[(size_t)(ua*16 + (i >> 8))*SD_ + hh*256 + (i & 255)];
    __syncthreads();
    const u16* Ku = Kb + (size_t)u*1024*SD_ + hh*256;
#pragma unroll
    for (int j = 0; j < 4; ++j) {
        const int n = t + j*256;
        const u16* kr = Ku + (size_t)n*SD_;
        float acc[16] = {};
        for (int d0 = 0; d0 < 256; d0 += 8) {
            u16x8 kv8 = *(const u16x8*)(kr + d0);
            float kf[8];
#pragma unroll
            for (int e = 0; e < 8; ++e) kf[e] = bf2f(kv8[e]);
#pragma unroll
            for (int k = 0; k < 16; ++k) {
                f32x4 q0 = *(const f32x4*)&qL[k][d0];
                f32x4 q1 = *(const f32x4*)&qL[k][d0+4];
                acc[k] += q0[0]*kf[0] + q0[1]*kf[1] + q0[2]*kf[2] + q0[3]*kf[3]
                        + q1[0]*kf[4] + q1[1]*kf[5] + q1[2]*kf[6] + q1[3]*kf[7];
            }
        }
#pragma unroll
        for (int k = 0; k < 16; ++k) sL[k][n] = acc[k] * 0.0625f;
    }
    __syncthreads();
    const int lane = t & 63, wv = t >> 6;
    for (int k = 0; k < 16; ++k) {
        float v0 = sL[k][t], v1 = sL[k][t+256], v2 = sL[k][t+512], v3 = sL[k][t+768];
        float mx = fmaxf(fmaxf(v0,v1), fmaxf(v2,v3));
#pragma unroll
        for (int o = 1; o < 64; o <<= 1) mx = fmaxf(mx, __shfl_xor(mx, o));
        if (lane == 0) red[wv] = mx;
        __syncthreads();
        mx = fmaxf(fmaxf(red[0],red[1]), fmaxf(red[2],red[3]));
        float e0 = expf(v0-mx), e1 = expf(v1-mx), e2 = expf(v2-mx), e3 = expf(v3-mx);
        float s = e0+e1+e2+e3;
#pragma unroll
        for (int o = 1; o < 64; o <<= 1) s += __shfl_xor(s, o);
        if (lane == 0) red[4+wv] = s;
        __syncthreads();
        s = red[4]+red[5]+red[6]+red[7];
        const float inv = 1.0f/s;
        float* Pr = P + ((size_t)(u*8+hh)*16 + k)*1024;
        Pr[t]=e0*inv; Pr[t+256]=e1*inv; Pr[t+512]=e2*inv; Pr[t+768]=e3*inv;
        __syncthreads();
    }
}

// ============ ctx: P @ V -> ctxb (bf16) ============
__global__ __launch_bounds__(256)
void ctx_u(const u16* __restrict__ Vb, const float* __restrict__ P,
           u16* __restrict__ ctxb)
{
    __shared__ float pL[16][1024];
    const int u = blockIdx.x >> 3, hh = blockIdx.x & 7;
    const int t = threadIdx.x;
    const float* Pu = P + (size_t)(u*8+hh)*16*1024;
    for (int i = t; i < 16*1024/4; i += 256)
        ((f32x4*)&pL[0][0])[i] = ((const f32x4*)Pu)[i];
    __syncthreads();
    const u16* Vu = Vb + (size_t)u*1024*SD_ + hh*256 + t;
    float acc[16] = {};
    for (int n = 0; n < 1024; n += 4) {
        float vv0 = bf2f(Vu[(size_t)n*SD_]);
        float vv1 = bf2f(Vu[(size_t)(n+1)*SD_]);
        float vv2 = bf2f(Vu[(size_t)(n+2)*SD_]);
        float vv3 = bf2f(Vu[(size_t)(n+3)*SD_]);
#pragma unroll
        for (int k = 0; k < 16; ++k) {
            f32x4 p4 = *(const f32x4*)&pL[k][n];
            acc[k] += p4[0]*vv0 + p4[1]*vv1 + p4[2]*vv2 + p4[3]*vv3;
        }
    }
#pragma unroll
    for (int k = 0; k < 16; ++k)
        ctxb[(size_t)u*16*SD_ + k*SD_ + hh*256 + t] = f2bf(acc[k]);
}

// ============ ow-GEMM: ctx2_u(16,2048) = ctxb_u @ owt_ua^T + bias ============
// grid (8 colblk, 24 u), 4 waves; wave covers 16x64 output
__global__ __launch_bounds__(256)
void gemm_ow(const u16* __restrict__ ctxb, const u16* __restrict__ Bslab,
             const float* __restrict__ biasSlab, const int* __restrict__ units_a,
             float* __restrict__ ctx2)
{
    const int u = blockIdx.y, ua = units_a[u];
    const int wave = threadIdx.x >> 6, lane = threadIdx.x & 63;
    const int col0 = blockIdx.x*256 + wave*64;
    const u16* A  = ctxb + (size_t)u*16*SD_;
    const u16* Bt = Bslab + (size_t)ua*SD_*SD_;
    const int fr = lane & 15, fk8 = (lane >> 4) << 3;
    f32x4 acc[4] = {};
    for (int k0 = 0; k0 < SD_; k0 += 32) {
        bf16x8 af = *(const bf16x8*)(A + (size_t)fr*SD_ + k0 + fk8);
#pragma unroll
        for (int n = 0; n < 4; ++n) {
            bf16x8 bf8 = *(const bf16x8*)(Bt + (size_t)(col0 + n*16 + fr)*SD_ + k0 + fk8);
            acc[n] = __builtin_amdgcn_mfma_f32_16x16x32_bf16(af, bf8, acc[n], 0, 0, 0);
        }
    }
    const int fq = lane >> 4;
#pragma unroll
    for (int n = 0; n < 4; ++n)
#pragma unroll
        for (int j = 0; j < 4; ++j) {
            const int row = fq*4 + j, col = col0 + n*16 + fr;
            ctx2[(size_t)u*16*SD_ + (size_t)row*SD_ + col] = acc[n][j] + biasSlab[ua*SD_ + col];
        }
}

// ============ final LN: LN(ctx2_u[k] + q_ua[k]) -> out or cspec ============
__global__ __launch_bounds__(256)
void ln_post_u(const float* __restrict__ ctx2, const float* __restrict__ qslab,
               const float* __restrict__ pgs, const float* __restrict__ pbs,
               const int* __restrict__ units_a, const int* __restrict__ units_b,
               float* __restrict__ out, float* __restrict__ cspec)
{
    const int k = blockIdx.x, u = blockIdx.y, tid = threadIdx.x;
    const int ua = units_a[u];
    const float* ip = ctx2 + ((size_t)u*16 + k)*SD_;
    const float* qr = qslab + ((size_t)ua*16 + k)*SD_;
    const float* g  = pgs + (size_t)ua*SD_;
    const float* bt = pbs + (size_t)ua*SD_;
    float f[8]; float s = 0.f, s2 = 0.f;
#pragma unroll
    for (int j = 0; j < 8; ++j) {
        const int c = tid + j*256;
        f[j] = ip[c] + qr[c];
        s += f[j]; s2 += f[j]*f[j];
    }
    __shared__ float sa[4], sb[4];
#pragma unroll
    for (int o = 32; o > 0; o >>= 1) { s += __shfl_down(s, o); s2 += __shfl_down(s2, o); }
    if ((tid & 63) == 0) { sa[tid >> 6] = s; sb[tid >> 6] = s2; }
    __syncthreads();
    s = sa[0]+sa[1]+sa[2]+sa[3]; s2 = sb[0]+sb[1]+sb[2]+sb[3];
    const float mean = s * (1.0f/SD_);
    const float inv  = rsqrtf(s2 * (1.0f/SD_) - mean*mean + 1e-5f);
    float* op = (u < 8) ? out + ((size_t)units_b[u]*32 + k)*SD_
                        : cspec + ((size_t)(u-8)*16 + k)*SD_;
#pragma unroll
    for (int j = 0; j < 8; ++j) { const int c = tid + j*256; op[c] = (f[j]-mean)*inv*g[c] + bt[c]; }
}

// ============ router ============
__global__ void pool_mean(const float* __restrict__ h, float* __restrict__ pooled) {
    const int c = blockIdx.x*256 + threadIdx.x;
    const int b = blockIdx.y;
    const float* p = h + (size_t)b*N_*TD_ + c;
    float s = 0.f;
    for (int n = 0; n < N_; ++n) s += p[(size_t)n*TD_];
    pooled[b*TD_ + c] = s * (1.0f/N_);
}

__global__ void router_mlp1(const float* __restrict__ pooled, const float* __restrict__ w1,
                            const float* __restrict__ b1, float* __restrict__ hid) {
    const int c = blockIdx.x*256 + threadIdx.x;   // 0..511
    const int b = blockIdx.y;
    const float* pr = pooled + b*TD_;
    float s = b1[c];
    for (int i = 0; i < TD_; ++i) s += pr[i] * w1[(size_t)i*512 + c];
    hid[b*512 + c] = gelu_exact(s);
}

__global__ void router_final(const float* __restrict__ hid, const float* __restrict__ w2,
                             const float* __restrict__ b2, float* __restrict__ probs,
                             int* __restrict__ widx, float* __restrict__ wval,
                             int* __restrict__ units_a, int* __restrict__ units_b) {
    __shared__ float lg[8][4];
    __shared__ int sw[16];
    const int tid = threadIdx.x;
    if (tid < 32) {
        const int b = tid >> 2, m = tid & 3;
        float s = b2[m];
        const float* hr = hid + b*512;
        for (int i = 0; i < 512; ++i) s += hr[i]*w2[i*4 + m];
        lg[b][m] = s;
    }
    __syncthreads();
    if (tid < 8) {
        const int b = tid;
        const float l0=lg[b][0], l1=lg[b][1], l2=lg[b][2], l3=lg[b][3];
        const float mx = fmaxf(fmaxf(l0,l1),fmaxf(l2,l3));
        const float e0=expf(l0-mx), e1=expf(l1-mx), e2=expf(l2-mx), e3=expf(l3-mx);
        const float s = e0+e1+e2+e3;
        float p[4] = {e0/s, e1/s, e2/s, e3/s};
        probs[b*4+0]=p[0]; probs[b*4+1]=p[1]; probs[b*4+2]=p[2]; probs[b*4+3]=p[3];
        int i0 = 0;
        for (int m = 1; m < 4; ++m) if (p[m] > p[i0]) i0 = m;
        int i1 = -1;
        for (int m = 0; m < 4; ++m) if (m != i0 && (i1 < 0 || p[m] > p[i1])) i1 = m;
        const float w0 = p[i0], w1 = p[i1], ws = w0 + w1 + 1e-8f;
        widx[b*2]=i0; widx[b*2+1]=i1;
        wval[b*2]=w0/ws; wval[b*2+1]=w1/ws;
        sw[b*2]=i0; sw[b*2+1]=i1;
    }
    __syncthreads();
    if (tid < 24) {
        units_a[tid] = (tid < 8) ? 0 : sw[tid-8] + 1;
        units_b[tid] = (tid < 8) ? tid : ((tid-8) >> 1);
    }
}

__global__ void combine_k(const float* __restrict__ cspec, const int* __restrict__ widx,
                          const float* __restrict__ wval, float* __restrict__ out) {
    const int i = blockIdx.x*256 + threadIdx.x;   // 65536 f32x4 over 8b*16k*512
    const int c4 = i & 511;
    const int k  = (i >> 9) & 15;
    const int b  = i >> 13;
    const float w0 = wval[b*2], w1 = wval[b*2+1];
    const f32x4 v0 = ((const f32x4*)cspec)[(size_t)((2*b)  *16 + k)*512 + c4];
    const f32x4 v1 = ((const f32x4*)cspec)[(size_t)((2*b+1)*16 + k)*512 + c4];
    ((f32x4*)out)[(size_t)(b*32 + 16 + k)*512 + c4] = v0*w0 + v1*w1;
}

// ============ pack helpers ============
__global__ void pack5(Ptr5 src, float* __restrict__ dst, int len) {
    int i = blockIdx.x*256 + threadIdx.x;
    if (i < 5*len) dst[i] = src.p[i/len][i%len];
}
__global__ void pack_slab8(Ptr40 s, float* __restrict__ dst) {
    int i = blockIdx.x*256 + threadIdx.x;    // 8*5*2048
    int slab = i / 10240, rem = i % 10240;
    dst[i] = s.p[slab][rem / 2048][rem % 2048];
}

// ============ host ============
extern "C" void kernel_launch(void* const* d_in, const int* in_sizes, int n_in,
                              void* d_out, int out_size, void* d_ws, size_t ws_size,
                              hipStream_t stream) {
    if (ws_size < 300300000ULL) return;

    const float* h = (const float*)d_in[0];
    const float* G[17]; const float* Sx[17];
    for (int i = 0; i < 17; ++i) { G[i] = (const float*)d_in[1+i]; Sx[i] = (const float*)d_in[18+i]; }
    const float* r_w1 = (const float*)d_in[35];
    const float* r_b1 = (const float*)d_in[36];
    const float* r_w2 = (const float*)d_in[37];
    const float* r_b2 = (const float*)d_in[38];

    static const size_t str[17] = {
        (size_t)TD_*BD_, BD_, (size_t)BD_*SD_, SD_, SD_, SD_, (size_t)K_*SD_,
        (size_t)SD_*SD_, (size_t)SD_*SD_, (size_t)SD_*SD_, (size_t)SD_*SD_,
        SD_, SD_, SD_, SD_, SD_, SD_ };
    auto P = [&](int pi, int a) -> const float* {
        return (a == 0) ? G[pi] : Sx[pi] + (size_t)(a-1)*str[pi];
    };

    char* w = (char*)d_ws;
    const size_t R0 = 0, R1 = 100663296, R2 = 201326592, R3 = 251658240, TAIL = 293601280;
    u16*   h_bf  = (u16*)(w + R0);            // 83.9MB, dead after down
    u16*   X     = (u16*)(w + R0);            // Y/X 100.7MB (up output, LN in place)
    u16*   wt_dw = (u16*)(w + R1);            // 52.4MB, dead after down
    u16*   Kbuf  = (u16*)(w + R1);            // 100.7MB (K then V)
    u16*   X1    = (u16*)(w + R2);            // 50.3MB, dead after up
    u16*   wt_v  = (u16*)(w + R2);            // 41.9MB (after up), dead after V-GEMM
    u16*   wt_ow = (u16*)(w + R2);            // 41.9MB (after V-GEMM)
    u16*   wt_uw = (u16*)(w + R3);            // 21MB, dead after up
    u16*   wt_k  = (u16*)(w + R3);            // 41.9MB (after up), dead after K-GEMM
    u16*   ctxb  = (u16*)(w + R3);            // 1.57MB (written at ctx; wt_k dead)
    float* ctx2  = (float*)(w + R3 + 1572864);   // 3.1MB
    float* cspec = (float*)(w + R3 + 4718592);   // 2.1MB
    float* Pbuf  = (float*)(w + R3 + 6815744);   // 12.6MB (scores; wt_k dead)
    float* qp_all  = (float*)(w + TAIL);             // 655360
    float* qslab   = (float*)(w + TAIL + 655360);    // 655360
    float* bias_dw = (float*)(w + TAIL + 1310720);   // 20480
    float* slab8   = (float*)(w + TAIL + 1331200);   // 327680: uw,k,v,ow,lng,lnb,pg,pb
    float* pooled  = (float*)(w + TAIL + 1658880);
    float* hid     = (float*)(w + TAIL + 1822720);
    int*   widx    = (int*)  (w + TAIL + 1839104);
    float* wval    = (float*)(w + TAIL + 1839168);
    int*   units_a = (int*)  (w + TAIL + 1839232);
    int*   units_b = (int*)  (w + TAIL + 1839328);

    float* bias_uw = slab8;
    float* bias_k  = slab8 + 1*5*SD_;
    float* bias_v  = slab8 + 2*5*SD_;
    float* bias_ow = slab8 + 3*5*SD_;
    float* lng     = slab8 + 4*5*SD_;
    float* lnb     = slab8 + 5*5*SD_;
    float* pgs     = slab8 + 6*5*SD_;
    float* pbs     = slab8 + 7*5*SD_;

    float* out = (float*)d_out;

    // ---- conversion + router ----
    cvt_bf16_flat<<<2048, 256, 0, stream>>>(h, h_bf, (long)((size_t)B_*N_*TD_/8));
    pool_mean<<<dim3(20, 8), 256, 0, stream>>>(h, pooled);
    router_mlp1<<<dim3(2, 8), 256, 0, stream>>>(pooled, r_w1, r_b1, hid);
    router_final<<<1, 64, 0, stream>>>(hid, r_w2, r_b2, out + 524288, widx, wval, units_a, units_b);

    // ---- q projections + packs ----
    Ptr5 q5, wq5, bq5, db5, qf5;
    for (int a = 0; a < 5; ++a) { q5.p[a]=P(6,a); wq5.p[a]=P(7,a); bq5.p[a]=P(11,a); db5.p[a]=P(1,a); qf5.p[a]=P(6,a); }
    qp_all_k<<<dim3(8, 5), 256, 0, stream>>>(q5, wq5, bq5, qp_all);
    pack5<<<20, 256, 0, stream>>>(db5, bias_dw, BD_);
    pack5<<<640, 256, 0, stream>>>(qf5, qslab, 16*SD_);
    Ptr40 s8;
    static const int slab_pi[8] = {3, 12, 13, 14, 4, 5, 15, 16};
    for (int si = 0; si < 8; ++si)
        for (int a = 0; a < 5; ++a) s8.p[si][a] = P(slab_pi[si], a);
    pack_slab8<<<320, 256, 0, stream>>>(s8, slab8);

    // ---- upfront transposes: dw -> R1, uw -> R3 ----
    for (int a = 0; a < 5; ++a) {
        cvt_transpose<<<dim3(TD_/64, BD_/64), 256, 0, stream>>>(P(0,a), wt_dw + (size_t)a*BD_*TD_, TD_, BD_);
        cvt_transpose<<<dim3(BD_/64, SD_/64), 256, 0, stream>>>(P(2,a), wt_uw + (size_t)a*SD_*BD_, BD_, SD_);
    }

    // ---- down-proj (gelu): 24 units, K=5120 ----
    gemm_units<1, 0><<<dim3(8, 8, 24), 256, 0, stream>>>(
        h_bf, wt_dw, (long)BD_*TD_, bias_dw, BD_, X1, BD_, (long)1024*BD_, TD_, units_a, units_b);

    // ---- up-proj: 24 units, K=1024 ----
    gemm_units<0, 1><<<dim3(8, 16, 24), 256, 0, stream>>>(
        X1, wt_uw, (long)SD_*BD_, bias_uw, SD_, X, SD_, (long)1024*SD_, BD_, units_a, units_b);

    // ---- LN in place ----
    ln_rows_u<<<24*1024, 256, 0, stream>>>(X, lng, lnb, units_a);

    // ---- transposes for K/V (wt_uw, X1 dead) ----
    for (int a = 0; a < 5; ++a) {
        cvt_transpose<<<dim3(SD_/64, SD_/64), 256, 0, stream>>>(P(8,a), wt_k + (size_t)a*SD_*SD_, SD_, SD_);
        cvt_transpose<<<dim3(SD_/64, SD_/64), 256, 0, stream>>>(P(9,a), wt_v + (size_t)a*SD_*SD_, SD_, SD_);
    }

    // ---- K projection ----
    gemm_units<0, 1><<<dim3(8, 16, 24), 256, 0, stream>>>(
        X, wt_k, (long)SD_*SD_, bias_k, SD_, Kbuf, SD_, (long)1024*SD_, SD_, units_a, units_b);

    // ---- scores + softmax ----
    scores_sm<<<24*8, 256, 0, stream>>>(Kbuf, qp_all, units_a, Pbuf);

    // ---- V projection (over K; K dead after scores) ----
    gemm_units<0, 1><<<dim3(8, 16, 24), 256, 0, stream>>>(
        X, wt_v, (long)SD_*SD_, bias_v, SD_, Kbuf, SD_, (long)1024*SD_, SD_, units_a, units_b);

    // ---- ow transpose (wt_v dead) ----
    for (int a = 0; a < 5; ++a)
        cvt_transpose<<<dim3(SD_/64, SD_/64), 256, 0, stream>>>(P(10,a), wt_ow + (size_t)a*SD_*SD_, SD_, SD_);

    // ---- ctx = P @ V ----
    ctx_u<<<24*8, 256, 0, stream>>>(Kbuf, Pbuf, ctxb);

    // ---- output projection ----
    gemm_ow<<<dim3(8, 24), 256, 0, stream>>>(ctxb, wt_ow, bias_ow, units_a, ctx2);

    // ---- final LN + combine ----
    ln_post_u<<<dim3(16, 24), 256, 0, stream>>>(ctx2, qslab, pgs, pbs, units_a, units_b, out, cspec);
    combine_k<<<256, 256, 0, stream>>>(cspec, widx, wval, out);
}

// Round 3
// 1603.864 us; speedup vs baseline: 1.9896x; 1.4456x over previous
//
#include <hip/hip_runtime.h>
#include <hip/hip_bf16.h>

#define B_   8
#define N_   1024
#define TD_  5120
#define SD_  2048
#define BD_  1024
#define K_   16
#define H_   8

typedef unsigned short u16;
typedef __attribute__((ext_vector_type(8))) short bf16x8;
typedef __attribute__((ext_vector_type(4))) float f32x4;
typedef __attribute__((ext_vector_type(8))) u16 u16x8;

__device__ __forceinline__ float bf2f(u16 u) {
    union { unsigned int i; float f; } x; x.i = ((unsigned)u) << 16; return x.f;
}
__device__ __forceinline__ u16 f2bf(float f) {
    union { float f; unsigned int i; } x; x.f = f;
    unsigned int i = x.i;
    return (u16)((i + 0x7fffu + ((i >> 16) & 1u)) >> 16);
}
__device__ __forceinline__ float gelu_exact(float v) {
    return 0.5f * v * (1.0f + erff(v * 0.70710678118654752f));
}
__device__ __forceinline__ void gload_lds16(const void* g, void* l) {
    __builtin_amdgcn_global_load_lds(
        (const __attribute__((address_space(1))) unsigned int*)g,
        (__attribute__((address_space(3))) unsigned int*)l, 16, 0, 0);
}

struct Ptr5 { const float* p[5]; };
struct Ptr40 { const float* p[8][5]; };

// ============ unit-indexed GEMM: C_u = epi(A_u @ Bt_ua^T + bias_ua) ============
template<int EPI, int AMODE>
__global__ __launch_bounds__(256, 2)
void gemm_units(const u16* __restrict__ Abase,
                const u16* __restrict__ Bbase, long bStride,
                const float* __restrict__ biasBase, int biasStride,
                u16* __restrict__ Cbase, int ldc, long cStride,
                int Kd, const int* __restrict__ units_a, const int* __restrict__ units_b)
{
    __shared__ u16 As[2*128*32];
    __shared__ u16 Bs[2*128*32];
    const int u = blockIdx.z;
    const int ua = units_a[u];
    const int ub = (AMODE == 0) ? units_b[u] : u;
    const u16* A  = Abase + (size_t)ub * 1024 * Kd;
    const u16* Bt = Bbase + (size_t)ua * bStride;
    const float* bias = biasBase + (size_t)ua * biasStride;
    u16* C = Cbase + (size_t)u * cStride;

    const int tid  = threadIdx.x;
    const int wave = tid >> 6, lane = tid & 63;
    const int row0 = blockIdx.x * 128, col0 = blockIdx.y * 128;
    const int wr = wave >> 1, wc = wave & 1;

    const int sr  = tid >> 2;
    const int cg  = (tid & 3) ^ ((sr >> 1) & 3);
    const char* aP0 = (const char*)(A  + (size_t)(row0 + sr)      * Kd + cg*8);
    const char* aP1 = (const char*)(A  + (size_t)(row0 + 64 + sr) * Kd + cg*8);
    const char* bP0 = (const char*)(Bt + (size_t)(col0 + sr)      * Kd + cg*8);
    const char* bP1 = (const char*)(Bt + (size_t)(col0 + 64 + sr) * Kd + cg*8);

    const int fr = lane & 15;
    const int chunk = (lane >> 4) ^ ((fr >> 1) & 3);
    int aoff[4], boff[4];
#pragma unroll
    for (int m = 0; m < 4; ++m) aoff[m] = (wr*64 + m*16 + fr)*32 + chunk*8;
#pragma unroll
    for (int n = 0; n < 4; ++n) boff[n] = (wc*64 + n*16 + fr)*32 + chunk*8;

    const int nkt = Kd >> 5;
    {
        char* asW = (char*)As + wave*1024;
        char* bsW = (char*)Bs + wave*1024;
        gload_lds16(aP0, asW);
        gload_lds16(aP1, asW + 4096);
        gload_lds16(bP0, bsW);
        gload_lds16(bP1, bsW + 4096);
    }
    asm volatile("s_waitcnt vmcnt(0)" ::: "memory");
    __syncthreads();

    f32x4 acc[4][4] = {};
    int cur = 0;
    for (int kt = 0; kt < nkt; ++kt) {
        if (kt + 1 < nkt) {
            const size_t kb = (size_t)(kt + 1) << 6;
            char* asN = (char*)As + (cur^1)*8192 + wave*1024;
            char* bsN = (char*)Bs + (cur^1)*8192 + wave*1024;
            gload_lds16(aP0 + kb, asN);
            gload_lds16(aP1 + kb, asN + 4096);
            gload_lds16(bP0 + kb, bsN);
            gload_lds16(bP1 + kb, bsN + 4096);
        }
        const u16* Ab = As + cur*4096;
        const u16* Bb = Bs + cur*4096;
        bf16x8 af[4], bfr[4];
#pragma unroll
        for (int m = 0; m < 4; ++m) af[m]  = *(const bf16x8*)(Ab + aoff[m]);
#pragma unroll
        for (int n = 0; n < 4; ++n) bfr[n] = *(const bf16x8*)(Bb + boff[n]);
#pragma unroll
        for (int m = 0; m < 4; ++m)
#pragma unroll
            for (int n = 0; n < 4; ++n)
                acc[m][n] = __builtin_amdgcn_mfma_f32_16x16x32_bf16(af[m], bfr[n], acc[m][n], 0, 0, 0);
        asm volatile("s_waitcnt vmcnt(0)" ::: "memory");
        __syncthreads();
        cur ^= 1;
    }

    const int fq = lane >> 4;
#pragma unroll
    for (int m = 0; m < 4; ++m)
#pragma unroll
        for (int n = 0; n < 4; ++n) {
            const int col = col0 + wc*64 + n*16 + fr;
            const float bv = bias[col];
#pragma unroll
            for (int j = 0; j < 4; ++j) {
                const int row = row0 + wr*64 + m*16 + fq*4 + j;
                float v = acc[m][n][j] + bv;
                if (EPI == 1) v = gelu_exact(v);
                C[(size_t)row*ldc + col] = f2bf(v);
            }
        }
}

// ============ conversions ============
__global__ void cvt_bf16_flat(const float* __restrict__ in, u16* __restrict__ out, long n8) {
    long i = (long)blockIdx.x * blockDim.x + threadIdx.x;
    const long stride = (long)gridDim.x * blockDim.x;
    for (; i < n8; i += stride) {
        const f32x4* p = (const f32x4*)in + i*2;
        f32x4 a = p[0], b = p[1];
        u16x8 o;
        o[0]=f2bf(a[0]); o[1]=f2bf(a[1]); o[2]=f2bf(a[2]); o[3]=f2bf(a[3]);
        o[4]=f2bf(b[0]); o[5]=f2bf(b[1]); o[6]=f2bf(b[2]); o[7]=f2bf(b[3]);
        ((u16x8*)out)[i] = o;
    }
}

__global__ __launch_bounds__(256)
void cvt_transpose(const float* __restrict__ W, u16* __restrict__ Wt, int Kd, int Nd) {
    __shared__ float t[64][65];
    const int k0 = blockIdx.x * 64, n0 = blockIdx.y * 64;
    const int tid = threadIdx.x;
#pragma unroll
    for (int i = 0; i < 4; ++i) {
        int ch = tid + i*256;
        int r = ch >> 4, c4 = (ch & 15) << 2;
        f32x4 v = *(const f32x4*)(W + (size_t)(k0 + r)*Nd + n0 + c4);
        t[r][c4] = v[0]; t[r][c4+1] = v[1]; t[r][c4+2] = v[2]; t[r][c4+3] = v[3];
    }
    __syncthreads();
#pragma unroll
    for (int i = 0; i < 2; ++i) {
        int ch = tid + i*256;
        int nr = ch >> 3, c8 = (ch & 7) << 3;
        u16x8 o;
#pragma unroll
        for (int j = 0; j < 8; ++j) o[j] = f2bf(t[c8 + j][nr]);
        *(u16x8*)(Wt + (size_t)(n0 + nr)*Kd + k0 + c8) = o;
    }
}

// ============ LayerNorm in place (bf16), unit-indexed params ============
__global__ __launch_bounds__(256)
void ln_rows_u(u16* __restrict__ X, const float* __restrict__ gslab,
               const float* __restrict__ bslab, const int* __restrict__ units_a) {
    const int row = blockIdx.x, tid = threadIdx.x;
    const int ua = units_a[row >> 10];
    const float* g  = gslab + (size_t)ua*SD_;
    const float* bt = bslab + (size_t)ua*SD_;
    u16* rp = X + (size_t)row*SD_;
    const u16x8 v = ((const u16x8*)rp)[tid];
    float f[8]; float s = 0.f, s2 = 0.f;
#pragma unroll
    for (int j = 0; j < 8; ++j) { f[j] = bf2f(v[j]); s += f[j]; s2 += f[j]*f[j]; }
    __shared__ float sa[4], sb[4];
#pragma unroll
    for (int o = 32; o > 0; o >>= 1) { s += __shfl_down(s, o); s2 += __shfl_down(s2, o); }
    if ((tid & 63) == 0) { sa[tid >> 6] = s; sb[tid >> 6] = s2; }
    __syncthreads();
    s = sa[0]+sa[1]+sa[2]+sa[3]; s2 = sb[0]+sb[1]+sb[2]+sb[3];
    const float mean = s * (1.0f/SD_);
    const float inv  = rsqrtf(s2 * (1.0f/SD_) - mean*mean + 1e-5f);
    const int c0 = tid*8;
    u16x8 o;
#pragma unroll
    for (int j = 0; j < 8; ++j) o[j] = f2bf((f[j]-mean)*inv*g[c0+j] + bt[c0+j]);
    ((u16x8*)rp)[tid] = o;
}

// ============ q-projection: split-K parallel ============
// grid (8 colblk, 5 a, 8 ksplit)
__global__ __launch_bounds__(256)
void qp_part(Ptr5 q, Ptr5 wq, float* __restrict__ Sp) {
    __shared__ float qL[16][256];
    const int a = blockIdx.y, ks = blockIdx.z;
    const int c = blockIdx.x*256 + threadIdx.x;
    const int t = threadIdx.x;
    const float* Q = q.p[a];
    for (int i = t; i < 16*256; i += 256)
        qL[i >> 8][i & 255] = Q[(size_t)(i >> 8)*SD_ + ks*256 + (i & 255)];
    __syncthreads();
    const float* W = wq.p[a] + (size_t)(ks*256)*SD_ + c;
    float acc[16] = {};
    for (int i = 0; i < 256; i += 4) {
        const float w0 = W[(size_t)i*SD_];
        const float w1 = W[(size_t)(i+1)*SD_];
        const float w2 = W[(size_t)(i+2)*SD_];
        const float w3 = W[(size_t)(i+3)*SD_];
#pragma unroll
        for (int k = 0; k < 16; ++k) {
            f32x4 q4 = *(const f32x4*)&qL[k][i];
            acc[k] += q4[0]*w0 + q4[1]*w1 + q4[2]*w2 + q4[3]*w3;
        }
    }
#pragma unroll
    for (int k = 0; k < 16; ++k)
        Sp[((size_t)(a*8 + ks)*16 + k)*SD_ + c] = acc[k];
}

// 5*16*2048 outputs
__global__ void qp_reduce(const float* __restrict__ Sp, Ptr5 bq, float* __restrict__ qp) {
    const int idx = blockIdx.x*256 + threadIdx.x;   // 163840
    const int a = idx >> 15, k = (idx >> 11) & 15, c = idx & 2047;
    float s = bq.p[a][c];
#pragma unroll
    for (int ks = 0; ks < 8; ++ks)
        s += Sp[((size_t)(a*8 + ks)*16 + k)*SD_ + c];
    qp[idx] = s;
}

// ============ fused scores + softmax -> P (f32) ============
__global__ __launch_bounds__(256)
void scores_sm(const u16* __restrict__ Kb, const float* __restrict__ qp,
               const int* __restrict__ units_a, float* __restrict__ P)
{
    __shared__ float sL[16][1024];
    __shared__ float qL[16][256];
    __shared__ float red[8];
    const int u = blockIdx.x >> 3, hh = blockIdx.x & 7;
    const int ua = units_a[u];
    const int t = threadIdx.x;
    for (int i = t; i < 16*256; i += 256)
        qL[i >> 8][i & 255] = qp[(size_t)(ua*16 + (i >> 8))*SD_ + hh*256 + (i & 255)];
    __syncthreads();
    const u16* Ku = Kb + (size_t)u*1024*SD_ + hh*256;
#pragma unroll
    for (int j = 0; j < 4; ++j) {
        const int n = t + j*256;
        const u16* kr = Ku + (size_t)n*SD_;
        float acc[16] = {};
        for (int d0 = 0; d0 < 256; d0 += 8) {
            u16x8 kv8 = *(const u16x8*)(kr + d0);
            float kf[8];
#pragma unroll
            for (int e = 0; e < 8; ++e) kf[e] = bf2f(kv8[e]);
#pragma unroll
            for (int k = 0; k < 16; ++k) {
                f32x4 q0 = *(const f32x4*)&qL[k][d0];
                f32x4 q1 = *(const f32x4*)&qL[k][d0+4];
                acc[k] += q0[0]*kf[0] + q0[1]*kf[1] + q0[2]*kf[2] + q0[3]*kf[3]
                        + q1[0]*kf[4] + q1[1]*kf[5] + q1[2]*kf[6] + q1[3]*kf[7];
            }
        }
#pragma unroll
        for (int k = 0; k < 16; ++k) sL[k][n] = acc[k] * 0.0625f;
    }
    __syncthreads();
    const int lane = t & 63, wv = t >> 6;
    for (int k = 0; k < 16; ++k) {
        float v0 = sL[k][t], v1 = sL[k][t+256], v2 = sL[k][t+512], v3 = sL[k][t+768];
        float mx = fmaxf(fmaxf(v0,v1), fmaxf(v2,v3));
#pragma unroll
        for (int o = 1; o < 64; o <<= 1) mx = fmaxf(mx, __shfl_xor(mx, o));
        if (lane == 0) red[wv] = mx;
        __syncthreads();
        mx = fmaxf(fmaxf(red[0],red[1]), fmaxf(red[2],red[3]));
        float e0 = expf(v0-mx), e1 = expf(v1-mx), e2 = expf(v2-mx), e3 = expf(v3-mx);
        float s = e0+e1+e2+e3;
#pragma unroll
        for (int o = 1; o < 64; o <<= 1) s += __shfl_xor(s, o);
        if (lane == 0) red[4+wv] = s;
        __syncthreads();
        s = red[4]+red[5]+red[6]+red[7];
        const float inv = 1.0f/s;
        float* Pr = P + ((size_t)(u*8+hh)*16 + k)*1024;
        Pr[t]=e0*inv; Pr[t+256]=e1*inv; Pr[t+512]=e2*inv; Pr[t+768]=e3*inv;
        __syncthreads();
    }
}

// ============ ctx: P @ V -> ctxb (bf16) ============
__global__ __launch_bounds__(256)
void ctx_u(const u16* __restrict__ Vb, const float* __restrict__ P,
           u16* __restrict__ ctxb)
{
    __shared__ float pL[16][1024];
    const int u = blockIdx.x >> 3, hh = blockIdx.x & 7;
    const int t = threadIdx.x;
    const float* Pu = P + (size_t)(u*8+hh)*16*1024;
    for (int i = t; i < 16*1024/4; i += 256)
        ((f32x4*)&pL[0][0])[i] = ((const f32x4*)Pu)[i];
    __syncthreads();
    const u16* Vu = Vb + (size_t)u*1024*SD_ + hh*256 + t;
    float acc[16] = {};
    for (int n = 0; n < 1024; n += 4) {
        float vv0 = bf2f(Vu[(size_t)n*SD_]);
        float vv1 = bf2f(Vu[(size_t)(n+1)*SD_]);
        float vv2 = bf2f(Vu[(size_t)(n+2)*SD_]);
        float vv3 = bf2f(Vu[(size_t)(n+3)*SD_]);
#pragma unroll
        for (int k = 0; k < 16; ++k) {
            f32x4 p4 = *(const f32x4*)&pL[k][n];
            acc[k] += p4[0]*vv0 + p4[1]*vv1 + p4[2]*vv2 + p4[3]*vv3;
        }
    }
#pragma unroll
    for (int k = 0; k < 16; ++k)
        ctxb[(size_t)u*16*SD_ + k*SD_ + hh*256 + t] = f2bf(acc[k]);
}

// ============ ow-GEMM ============
__global__ __launch_bounds__(256)
void gemm_ow(const u16* __restrict__ ctxb, const u16* __restrict__ Bslab,
             const float* __restrict__ biasSlab, const int* __restrict__ units_a,
             float* __restrict__ ctx2)
{
    const int u = blockIdx.y, ua = units_a[u];
    const int wave = threadIdx.x >> 6, lane = threadIdx.x & 63;
    const int col0 = blockIdx.x*256 + wave*64;
    const u16* A  = ctxb + (size_t)u*16*SD_;
    const u16* Bt = Bslab + (size_t)ua*SD_*SD_;
    const int fr = lane & 15, fk8 = (lane >> 4) << 3;
    f32x4 acc[4] = {};
    for (int k0 = 0; k0 < SD_; k0 += 32) {
        bf16x8 af = *(const bf16x8*)(A + (size_t)fr*SD_ + k0 + fk8);
#pragma unroll
        for (int n = 0; n < 4; ++n) {
            bf16x8 bf8 = *(const bf16x8*)(Bt + (size_t)(col0 + n*16 + fr)*SD_ + k0 + fk8);
            acc[n] = __builtin_amdgcn_mfma_f32_16x16x32_bf16(af, bf8, acc[n], 0, 0, 0);
        }
    }
    const int fq = lane >> 4;
#pragma unroll
    for (int n = 0; n < 4; ++n)
#pragma unroll
        for (int j = 0; j < 4; ++j) {
            const int row = fq*4 + j, col = col0 + n*16 + fr;
            ctx2[(size_t)u*16*SD_ + (size_t)row*SD_ + col] = acc[n][j] + biasSlab[ua*SD_ + col];
        }
}

// ============ final LN ============
__global__ __launch_bounds__(256)
void ln_post_u(const float* __restrict__ ctx2, const float* __restrict__ qslab,
               const float* __restrict__ pgs, const float* __restrict__ pbs,
               const int* __restrict__ units_a, const int* __restrict__ units_b,
               float* __restrict__ out, float* __restrict__ cspec)
{
    const int k = blockIdx.x, u = blockIdx.y, tid = threadIdx.x;
    const int ua = units_a[u];
    const float* ip = ctx2 + ((size_t)u*16 + k)*SD_;
    const float* qr = qslab + ((size_t)ua*16 + k)*SD_;
    const float* g  = pgs + (size_t)ua*SD_;
    const float* bt = pbs + (size_t)ua*SD_;
    float f[8]; float s = 0.f, s2 = 0.f;
#pragma unroll
    for (int j = 0; j < 8; ++j) {
        const int c = tid + j*256;
        f[j] = ip[c] + qr[c];
        s += f[j]; s2 += f[j]*f[j];
    }
    __shared__ float sa[4], sb[4];
#pragma unroll
    for (int o = 32; o > 0; o >>= 1) { s += __shfl_down(s, o); s2 += __shfl_down(s2, o); }
    if ((tid & 63) == 0) { sa[tid >> 6] = s; sb[tid >> 6] = s2; }
    __syncthreads();
    s = sa[0]+sa[1]+sa[2]+sa[3]; s2 = sb[0]+sb[1]+sb[2]+sb[3];
    const float mean = s * (1.0f/SD_);
    const float inv  = rsqrtf(s2 * (1.0f/SD_) - mean*mean + 1e-5f);
    float* op = (u < 8) ? out + ((size_t)units_b[u]*32 + k)*SD_
                        : cspec + ((size_t)(u-8)*16 + k)*SD_;
#pragma unroll
    for (int j = 0; j < 8; ++j) { const int c = tid + j*256; op[c] = (f[j]-mean)*inv*g[c] + bt[c]; }
}

// ============ router (parallel split) ============
__global__ __launch_bounds__(256)
void pool_part(const float* __restrict__ h, float* __restrict__ pp) {
    const int c = blockIdx.x*256 + threadIdx.x;
    const int b = blockIdx.y, ns = blockIdx.z;
    const float* p = h + ((size_t)b*N_ + ns*256)*TD_ + c;
    float s = 0.f;
    for (int n = 0; n < 256; ++n) s += p[(size_t)n*TD_];
    pp[(size_t)ns*8*TD_ + (size_t)b*TD_ + c] = s;
}
__global__ void pool_reduce(const float* __restrict__ pp, float* __restrict__ pooled) {
    const int idx = blockIdx.x*256 + threadIdx.x;   // 40960
    const float s = pp[idx] + pp[idx + 8*TD_] + pp[idx + 16*TD_] + pp[idx + 24*TD_];
    pooled[idx] = s * (1.0f/N_);
}

__global__ __launch_bounds__(256)
void rmlp_part(const float* __restrict__ pooled, const float* __restrict__ w1,
               float* __restrict__ rp) {
    const int c = blockIdx.x*256 + threadIdx.x;   // 0..511
    const int b = blockIdx.y, is = blockIdx.z;    // is: 10 chunks of 512
    const float* pr = pooled + b*TD_ + is*512;
    const float* W = w1 + (size_t)(is*512)*512 + c;
    float s = 0.f;
    for (int i = 0; i < 512; ++i) s += pr[i] * W[(size_t)i*512];
    rp[(b*10 + is)*512 + c] = s;
}
__global__ void rmlp_reduce(const float* __restrict__ rp, const float* __restrict__ b1,
                            float* __restrict__ hid) {
    const int idx = blockIdx.x*256 + threadIdx.x;   // 4096
    const int b = idx >> 9, c = idx & 511;
    float s = b1[c];
#pragma unroll
    for (int is = 0; is < 10; ++is) s += rp[(b*10 + is)*512 + c];
    hid[idx] = gelu_exact(s);
}

__global__ void router_final(const float* __restrict__ hid, const float* __restrict__ w2,
                             const float* __restrict__ b2, float* __restrict__ probs,
                             int* __restrict__ widx, float* __restrict__ wval,
                             int* __restrict__ units_a, int* __restrict__ units_b) {
    __shared__ float lg[8][4];
    __shared__ int sw[16];
    const int tid = threadIdx.x;
    if (tid < 32) {
        const int b = tid >> 2, m = tid & 3;
        float s = b2[m];
        const float* hr = hid + b*512;
        for (int i = 0; i < 512; ++i) s += hr[i]*w2[i*4 + m];
        lg[b][m] = s;
    }
    __syncthreads();
    if (tid < 8) {
        const int b = tid;
        const float l0=lg[b][0], l1=lg[b][1], l2=lg[b][2], l3=lg[b][3];
        const float mx = fmaxf(fmaxf(l0,l1),fmaxf(l2,l3));
        const float e0=expf(l0-mx), e1=expf(l1-mx), e2=expf(l2-mx), e3=expf(l3-mx);
        const float s = e0+e1+e2+e3;
        float p[4] = {e0/s, e1/s, e2/s, e3/s};
        probs[b*4+0]=p[0]; probs[b*4+1]=p[1]; probs[b*4+2]=p[2]; probs[b*4+3]=p[3];
        int i0 = 0;
        for (int m = 1; m < 4; ++m) if (p[m] > p[i0]) i0 = m;
        int i1 = -1;
        for (int m = 0; m < 4; ++m) if (m != i0 && (i1 < 0 || p[m] > p[i1])) i1 = m;
        const float w0 = p[i0], w1 = p[i1], ws = w0 + w1 + 1e-8f;
        widx[b*2]=i0; widx[b*2+1]=i1;
        wval[b*2]=w0/ws; wval[b*2+1]=w1/ws;
        sw[b*2]=i0; sw[b*2+1]=i1;
    }
    __syncthreads();
    if (tid < 24) {
        units_a[tid] = (tid < 8) ? 0 : sw[tid-8] + 1;
        units_b[tid] = (tid < 8) ? tid : ((tid-8) >> 1);
    }
}

__global__ void combine_k(const float* __restrict__ cspec, const int* __restrict__ widx,
                          const float* __restrict__ wval, float* __restrict__ out) {
    const int i = blockIdx.x*256 + threadIdx.x;
    const int c4 = i & 511;
    const int k  = (i >> 9) & 15;
    const int b  = i >> 13;
    const float w0 = wval[b*2], w1 = wval[b*2+1];
    const f32x4 v0 = ((const f32x4*)cspec)[(size_t)((2*b)  *16 + k)*512 + c4];
    const f32x4 v1 = ((const f32x4*)cspec)[(size_t)((2*b+1)*16 + k)*512 + c4];
    ((f32x4*)out)[(size_t)(b*32 + 16 + k)*512 + c4] = v0*w0 + v1*w1;
}

// ============ pack helpers ============
__global__ void pack5(Ptr5 src, float* __restrict__ dst, int len) {
    int i = blockIdx.x*256 + threadIdx.x;
    if (i < 5*len) dst[i] = src.p[i/len][i%len];
}
__global__ void pack_slab8(Ptr40 s, float* __restrict__ dst) {
    int i = blockIdx.x*256 + threadIdx.x;
    int slab = i / 10240, rem = i % 10240;
    dst[i] = s.p[slab][rem / 2048][rem % 2048];
}

// ============ host ============
extern "C" void kernel_launch(void* const* d_in, const int* in_sizes, int n_in,
                              void* d_out, int out_size, void* d_ws, size_t ws_size,
                              hipStream_t stream) {
    if (ws_size < 300300000ULL) return;

    const float* h = (const float*)d_in[0];
    const float* G[17]; const float* Sx[17];
    for (int i = 0; i < 17; ++i) { G[i] = (const float*)d_in[1+i]; Sx[i] = (const float*)d_in[18+i]; }
    const float* r_w1 = (const float*)d_in[35];
    const float* r_b1 = (const float*)d_in[36];
    const float* r_w2 = (const float*)d_in[37];
    const float* r_b2 = (const float*)d_in[38];

    static const size_t str[17] = {
        (size_t)TD_*BD_, BD_, (size_t)BD_*SD_, SD_, SD_, SD_, (size_t)K_*SD_,
        (size_t)SD_*SD_, (size_t)SD_*SD_, (size_t)SD_*SD_, (size_t)SD_*SD_,
        SD_, SD_, SD_, SD_, SD_, SD_ };
    auto P = [&](int pi, int a) -> const float* {
        return (a == 0) ? G[pi] : Sx[pi] + (size_t)(a-1)*str[pi];
    };

    char* w = (char*)d_ws;
    const size_t R0 = 0, R1 = 100663296, R2 = 201326592, R3 = 251658240, TAIL = 293601280;
    u16*   h_bf  = (u16*)(w + R0);
    u16*   X     = (u16*)(w + R0);
    u16*   wt_dw = (u16*)(w + R1);
    u16*   Kbuf  = (u16*)(w + R1);
    u16*   X1    = (u16*)(w + R2);
    u16*   wt_v  = (u16*)(w + R2);
    u16*   wt_ow = (u16*)(w + R2);
    u16*   wt_uw = (u16*)(w + R3);
    u16*   wt_k  = (u16*)(w + R3);
    u16*   ctxb  = (u16*)(w + R3);
    float* ctx2  = (float*)(w + R3 + 1572864);
    float* cspec = (float*)(w + R3 + 4718592);
    float* Pbuf  = (float*)(w + R3 + 6815744);
    // scratch for split-K partials lives in R2 (dead until down-GEMM writes X1)
    float* qpp   = (float*)(w + R2);               // 10.5 MB
    float* poolp = (float*)(w + R2 + 12582912);    // 655 KB
    float* routp = (float*)(w + R2 + 14680064);    // 164 KB
    float* qp_all  = (float*)(w + TAIL);
    float* qslab   = (float*)(w + TAIL + 655360);
    float* bias_dw = (float*)(w + TAIL + 1310720);
    float* slab8   = (float*)(w + TAIL + 1331200);
    float* pooled  = (float*)(w + TAIL + 1658880);
    float* hid     = (float*)(w + TAIL + 1822720);
    int*   widx    = (int*)  (w + TAIL + 1839104);
    float* wval    = (float*)(w + TAIL + 1839168);
    int*   units_a = (int*)  (w + TAIL + 1839232);
    int*   units_b = (int*)  (w + TAIL + 1839328);

    float* bias_uw = slab8;
    float* bias_k  = slab8 + 1*5*SD_;
    float* bias_v  = slab8 + 2*5*SD_;
    float* bias_ow = slab8 + 3*5*SD_;
    float* lng     = slab8 + 4*5*SD_;
    float* lnb     = slab8 + 5*5*SD_;
    float* pgs     = slab8 + 6*5*SD_;
    float* pbs     = slab8 + 7*5*SD_;

    float* out = (float*)d_out;

    // ---- conversion + router (parallel) ----
    cvt_bf16_flat<<<2048, 256, 0, stream>>>(h, h_bf, (long)((size_t)B_*N_*TD_/8));
    pool_part<<<dim3(20, 8, 4), 256, 0, stream>>>(h, poolp);
    pool_reduce<<<160, 256, 0, stream>>>(poolp, pooled);
    rmlp_part<<<dim3(2, 8, 10), 256, 0, stream>>>(pooled, r_w1, routp);
    rmlp_reduce<<<16, 256, 0, stream>>>(routp, r_b1, hid);
    router_final<<<1, 64, 0, stream>>>(hid, r_w2, r_b2, out + 524288, widx, wval, units_a, units_b);

    // ---- q projections (split-K) + packs ----
    Ptr5 q5, wq5, bq5, db5;
    for (int a = 0; a < 5; ++a) { q5.p[a]=P(6,a); wq5.p[a]=P(7,a); bq5.p[a]=P(11,a); db5.p[a]=P(1,a); }
    qp_part<<<dim3(8, 5, 8), 256, 0, stream>>>(q5, wq5, qpp);
    qp_reduce<<<640, 256, 0, stream>>>(qpp, bq5, qp_all);
    pack5<<<20, 256, 0, stream>>>(db5, bias_dw, BD_);
    pack5<<<640, 256, 0, stream>>>(q5, qslab, 16*SD_);
    Ptr40 s8;
    static const int slab_pi[8] = {3, 12, 13, 14, 4, 5, 15, 16};
    for (int si = 0; si < 8; ++si)
        for (int a = 0; a < 5; ++a) s8.p[si][a] = P(slab_pi[si], a);
    pack_slab8<<<320, 256, 0, stream>>>(s8, slab8);

    // ---- upfront transposes ----
    for (int a = 0; a < 5; ++a) {
        cvt_transpose<<<dim3(TD_/64, BD_/64), 256, 0, stream>>>(P(0,a), wt_dw + (size_t)a*BD_*TD_, TD_, BD_);
        cvt_transpose<<<dim3(BD_/64, SD_/64), 256, 0, stream>>>(P(2,a), wt_uw + (size_t)a*SD_*BD_, BD_, SD_);
    }

    // ---- down-proj (gelu) ----
    gemm_units<1, 0><<<dim3(8, 8, 24), 256, 0, stream>>>(
        h_bf, wt_dw, (long)BD_*TD_, bias_dw, BD_, X1, BD_, (long)1024*BD_, TD_, units_a, units_b);

    // ---- up-proj ----
    gemm_units<0, 1><<<dim3(8, 16, 24), 256, 0, stream>>>(
        X1, wt_uw, (long)SD_*BD_, bias_uw, SD_, X, SD_, (long)1024*SD_, BD_, units_a, units_b);

    // ---- LN in place ----
    ln_rows_u<<<24*1024, 256, 0, stream>>>(X, lng, lnb, units_a);

    // ---- transposes for K/V ----
    for (int a = 0; a < 5; ++a) {
        cvt_transpose<<<dim3(SD_/64, SD_/64), 256, 0, stream>>>(P(8,a), wt_k + (size_t)a*SD_*SD_, SD_, SD_);
        cvt_transpose<<<dim3(SD_/64, SD_/64), 256, 0, stream>>>(P(9,a), wt_v + (size_t)a*SD_*SD_, SD_, SD_);
    }

    // ---- K projection ----
    gemm_units<0, 1><<<dim3(8, 16, 24), 256, 0, stream>>>(
        X, wt_k, (long)SD_*SD_, bias_k, SD_, Kbuf, SD_, (long)1024*SD_, SD_, units_a, units_b);

    // ---- scores + softmax ----
    scores_sm<<<24*8, 256, 0, stream>>>(Kbuf, qp_all, units_a, Pbuf);

    // ---- V projection ----
    gemm_units<0, 1><<<dim3(8, 16, 24), 256, 0, stream>>>(
        X, wt_v, (long)SD_*SD_, bias_v, SD_, Kbuf, SD_, (long)1024*SD_, SD_, units_a, units_b);

    // ---- ow transpose ----
    for (int a = 0; a < 5; ++a)
        cvt_transpose<<<dim3(SD_/64, SD_/64), 256, 0, stream>>>(P(10,a), wt_ow + (size_t)a*SD_*SD_, SD_, SD_);

    // ---- ctx = P @ V ----
    ctx_u<<<24*8, 256, 0, stream>>>(Kbuf, Pbuf, ctxb);

    // ---- output projection ----
    gemm_ow<<<dim3(8, 24), 256, 0, stream>>>(ctxb, wt_ow, bias_ow, units_a, ctx2);

    // ---- final LN + combine ----
    ln_post_u<<<dim3(16, 24), 256, 0, stream>>>(ctx2, qslab, pgs, pbs, units_a, units_b, out, cspec);
    combine_k<<<256, 256, 0, stream>>>(cspec, widx, wval, out);
}

// Round 6
// 1440.573 us; speedup vs baseline: 2.2152x; 1.1134x over previous
//
#include <hip/hip_runtime.h>
#include <hip/hip_bf16.h>

#define B_   8
#define N_   1024
#define TD_  5120
#define SD_  2048
#define BD_  1024
#define K_   16
#define H_   8

typedef unsigned short u16;
typedef __attribute__((ext_vector_type(8))) short bf16x8;
typedef __attribute__((ext_vector_type(4))) float f32x4;
typedef __attribute__((ext_vector_type(8))) u16 u16x8;

__device__ __forceinline__ float bf2f(u16 u) {
    union { unsigned int i; float f; } x; x.i = ((unsigned)u) << 16; return x.f;
}
__device__ __forceinline__ u16 f2bf(float f) {
    union { float f; unsigned int i; } x; x.f = f;
    unsigned int i = x.i;
    return (u16)((i + 0x7fffu + ((i >> 16) & 1u)) >> 16);
}
__device__ __forceinline__ float gelu_exact(float v) {
    return 0.5f * v * (1.0f + erff(v * 0.70710678118654752f));
}
__device__ __forceinline__ void gload_lds16(const void* g, void* l) {
    __builtin_amdgcn_global_load_lds(
        (const __attribute__((address_space(1))) unsigned int*)g,
        (__attribute__((address_space(3))) unsigned int*)l, 16, 0, 0);
}

struct Ptr5 { const float* p[5]; };
struct Ptr40 { const float* p[8][5]; };

// ============ 256x256 counted-vmcnt pipelined GEMM, unit-indexed ============
// 512 threads (8 waves, 2M x 4N), BK=64, 128 KB LDS double buffer, XOR-swizzle.
// Phase skeleton (m201): STAGE; vmcnt(N); barrier; fence; ds_reads;
// lgkmcnt(0); MFMA; barrier.
// FIXED r5->r6: B-fragment LDS row is wn*64 + nf*16 + fr, matching the
// C-epilogue column block (was nf*64 + wn*16 -> column permutation bug).
template<int EPI, int AMODE>
__global__ __launch_bounds__(512, 2)
void gemm256(const u16* __restrict__ Abase,
             const u16* __restrict__ Bbase, long bStride,
             const float* __restrict__ biasBase, int biasStride,
             u16* __restrict__ Cbase, int ldc, long cStride, int Kd,
             const int* __restrict__ units_a, const int* __restrict__ units_b)
{
    __shared__ char lds[131072];
    const int u = blockIdx.z;
    const int ua = units_a[u];
    const int ub = (AMODE == 0) ? units_b[u] : u;
    const u16* A  = Abase + (size_t)ub * 1024 * Kd;
    const u16* Bt = Bbase + (size_t)ua * bStride;
    const float* bias = biasBase + (size_t)ua * biasStride;
    u16* C = Cbase + (size_t)u * cStride;

    const int tid  = threadIdx.x;
    const int wave = tid >> 6, lane = tid & 63;
    const int wm = wave >> 2, wn = wave & 3;
    const int row0 = blockIdx.x * 256, col0 = blockIdx.y * 256;

    // staging source (pre-swizzled column so linear LDS dest = swizzled layout)
    const int srow = tid >> 3;
    const int scol = ((tid & 7) ^ ((tid >> 3) & 7)) << 3;   // elems
    const char* aSrc = (const char*)(A  + (size_t)(row0 + srow) * Kd + scol);
    const char* bSrc = (const char*)(Bt + (size_t)(col0 + srow) * Kd + scol);
    const int ldsW = wave * 1024;

    const int fr = lane & 15, fq = lane >> 4;
    const int kl  = fq << 4;            // byte offset of lane's k-chunk
    const int swz = (fr & 7) << 4;

    f32x4 acc[8][4] = {};
    bf16x8 aF[4], bF[4];

#define STAGE_A(bufv, hh, kt) do { \
    const char* s_ = aSrc + ((size_t)((hh)*128) * Kd + (size_t)(kt) * 64) * 2; \
    char* d_ = lds + (bufv)*65536 + (hh)*16384 + ldsW; \
    gload_lds16(s_, d_); \
    gload_lds16(s_ + (size_t)64 * Kd * 2, d_ + 8192); } while(0)
#define STAGE_B(bufv, hh, kt) do { \
    const char* s_ = bSrc + ((size_t)((hh)*128) * Kd + (size_t)(kt) * 64) * 2; \
    char* d_ = lds + (bufv)*65536 + 32768 + (hh)*16384 + ldsW; \
    gload_lds16(s_, d_); \
    gload_lds16(s_ + (size_t)64 * Kd * 2, d_ + 8192); } while(0)

#define LDA_(bufv, mf, kk) (*(const bf16x8*)(lds + (bufv)*65536 + \
    ((mf)*32 + wm*16 + fr)*128 + ((((kk)*64) + kl) ^ swz)))
#define LDB_(bufv, nf, kk) (*(const bf16x8*)(lds + (bufv)*65536 + 32768 + \
    (wn*64 + (nf)*16 + fr)*128 + ((((kk)*64) + kl) ^ swz)))

#define FENCE_ asm volatile("" ::: "memory")
#define BAR_   __builtin_amdgcn_s_barrier()
#define WAITL_ asm volatile("s_waitcnt lgkmcnt(0)" ::: "memory")
#define VM_(n) asm volatile("s_waitcnt vmcnt(" #n ")" ::: "memory")

#define READ_B(bufv, kk) { _Pragma("unroll") \
    for (int n_ = 0; n_ < 4; ++n_) bF[n_] = LDB_(bufv, n_, kk); }
#define READ_A(bufv, mh, kk) { _Pragma("unroll") \
    for (int i_ = 0; i_ < 4; ++i_) aF[i_] = LDA_(bufv, (mh)*4 + i_, kk); }
#define MFMA_(mh) { __builtin_amdgcn_s_setprio(1); \
    _Pragma("unroll") for (int i_ = 0; i_ < 4; ++i_) { \
      _Pragma("unroll") for (int n_ = 0; n_ < 4; ++n_) \
        acc[(mh)*4+i_][n_] = __builtin_amdgcn_mfma_f32_16x16x32_bf16( \
            aF[i_], bF[n_], acc[(mh)*4+i_][n_], 0, 0, 0); } \
    __builtin_amdgcn_s_setprio(0); }

    // prologue: tile 0 -> buf0 (8 loads in flight: A0,B0,B1,A1)
    STAGE_A(0, 0, 0);
    STAGE_B(0, 0, 0);
    STAGE_B(0, 1, 0);
    STAGE_A(0, 1, 0);

    const int nt = Kd >> 6;
    for (int T = 0; T < nt - 1; ++T) {
        const int bufv = T & 1, nb = bufv ^ 1;
        // P1: reads B(kk0)+A0(kk0) -- gated by vmcnt(4) retiring A0,B0,B1
        STAGE_A(nb, 0, T + 1);
        VM_(4); BAR_; FENCE_;
        READ_B(bufv, 0); READ_A(bufv, 0, 0);
        WAITL_; MFMA_(0); BAR_;
        // P2: reads A1(kk0) -- gated by vmcnt(4) retiring A1
        STAGE_B(nb, 0, T + 1);
        VM_(4); BAR_; FENCE_;
        READ_A(bufv, 1, 0);
        WAITL_; MFMA_(1); BAR_;
        // P3: kk1 of B/A0 (gated in P1); reads issue pre-barrier
        READ_B(bufv, 1); READ_A(bufv, 0, 1);
        STAGE_B(nb, 1, T + 1);
        BAR_; WAITL_; MFMA_(0); BAR_;
        // P4: kk1 of A1 (gated in P2)
        READ_A(bufv, 1, 1);
        STAGE_A(nb, 1, T + 1);
        BAR_; WAITL_; MFMA_(1); BAR_;
    }
    {
        const int bufv = (nt - 1) & 1;
        VM_(2); BAR_; FENCE_;
        READ_B(bufv, 0); READ_A(bufv, 0, 0);
        WAITL_; MFMA_(0); BAR_;
        VM_(0); BAR_; FENCE_;
        READ_A(bufv, 1, 0);
        WAITL_; MFMA_(1);
        READ_B(bufv, 1); READ_A(bufv, 0, 1);
        WAITL_; MFMA_(0);
        READ_A(bufv, 1, 1);
        WAITL_; MFMA_(1);
    }

#undef STAGE_A
#undef STAGE_B
#undef LDA_
#undef LDB_
#undef FENCE_
#undef BAR_
#undef WAITL_
#undef VM_
#undef READ_B
#undef READ_A
#undef MFMA_

#pragma unroll
    for (int mf = 0; mf < 8; ++mf)
#pragma unroll
        for (int nf = 0; nf < 4; ++nf) {
            const int col = col0 + wn*64 + nf*16 + fr;
            const float bv = bias[col];
#pragma unroll
            for (int j = 0; j < 4; ++j) {
                const int row = row0 + mf*32 + wm*16 + fq*4 + j;
                float v = acc[mf][nf][j] + bv;
                if (EPI == 1) v = gelu_exact(v);
                C[(size_t)row*ldc + col] = f2bf(v);
            }
        }
}

// ============ conversions ============
__global__ void cvt_bf16_flat(const float* __restrict__ in, u16* __restrict__ out, long n8) {
    long i = (long)blockIdx.x * blockDim.x + threadIdx.x;
    const long stride = (long)gridDim.x * blockDim.x;
    for (; i < n8; i += stride) {
        const f32x4* p = (const f32x4*)in + i*2;
        f32x4 a = p[0], b = p[1];
        u16x8 o;
        o[0]=f2bf(a[0]); o[1]=f2bf(a[1]); o[2]=f2bf(a[2]); o[3]=f2bf(a[3]);
        o[4]=f2bf(b[0]); o[5]=f2bf(b[1]); o[6]=f2bf(b[2]); o[7]=f2bf(b[3]);
        ((u16x8*)out)[i] = o;
    }
}

__global__ __launch_bounds__(256)
void cvt_transpose(const float* __restrict__ W, u16* __restrict__ Wt, int Kd, int Nd) {
    __shared__ float t[64][65];
    const int k0 = blockIdx.x * 64, n0 = blockIdx.y * 64;
    const int tid = threadIdx.x;
#pragma unroll
    for (int i = 0; i < 4; ++i) {
        int ch = tid + i*256;
        int r = ch >> 4, c4 = (ch & 15) << 2;
        f32x4 v = *(const f32x4*)(W + (size_t)(k0 + r)*Nd + n0 + c4);
        t[r][c4] = v[0]; t[r][c4+1] = v[1]; t[r][c4+2] = v[2]; t[r][c4+3] = v[3];
    }
    __syncthreads();
#pragma unroll
    for (int i = 0; i < 2; ++i) {
        int ch = tid + i*256;
        int nr = ch >> 3, c8 = (ch & 7) << 3;
        u16x8 o;
#pragma unroll
        for (int j = 0; j < 8; ++j) o[j] = f2bf(t[c8 + j][nr]);
        *(u16x8*)(Wt + (size_t)(n0 + nr)*Kd + k0 + c8) = o;
    }
}

// ============ LayerNorm in place (bf16), unit-indexed params ============
__global__ __launch_bounds__(256)
void ln_rows_u(u16* __restrict__ X, const float* __restrict__ gslab,
               const float* __restrict__ bslab, const int* __restrict__ units_a) {
    const int row = blockIdx.x, tid = threadIdx.x;
    const int ua = units_a[row >> 10];
    const float* g  = gslab + (size_t)ua*SD_;
    const float* bt = bslab + (size_t)ua*SD_;
    u16* rp = X + (size_t)row*SD_;
    const u16x8 v = ((const u16x8*)rp)[tid];
    float f[8]; float s = 0.f, s2 = 0.f;
#pragma unroll
    for (int j = 0; j < 8; ++j) { f[j] = bf2f(v[j]); s += f[j]; s2 += f[j]*f[j]; }
    __shared__ float sa[4], sb[4];
#pragma unroll
    for (int o = 32; o > 0; o >>= 1) { s += __shfl_down(s, o); s2 += __shfl_down(s2, o); }
    if ((tid & 63) == 0) { sa[tid >> 6] = s; sb[tid >> 6] = s2; }
    __syncthreads();
    s = sa[0]+sa[1]+sa[2]+sa[3]; s2 = sb[0]+sb[1]+sb[2]+sb[3];
    const float mean = s * (1.0f/SD_);
    const float inv  = rsqrtf(s2 * (1.0f/SD_) - mean*mean + 1e-5f);
    const int c0 = tid*8;
    u16x8 o;
#pragma unroll
    for (int j = 0; j < 8; ++j) o[j] = f2bf((f[j]-mean)*inv*g[c0+j] + bt[c0+j]);
    ((u16x8*)rp)[tid] = o;
}

// ============ q-projection: split-K parallel ============
__global__ __launch_bounds__(256)
void qp_part(Ptr5 q, Ptr5 wq, float* __restrict__ Sp) {
    __shared__ float qL[16][256];
    const int a = blockIdx.y, ks = blockIdx.z;
    const int c = blockIdx.x*256 + threadIdx.x;
    const int t = threadIdx.x;
    const float* Q = q.p[a];
    for (int i = t; i < 16*256; i += 256)
        qL[i >> 8][i & 255] = Q[(size_t)(i >> 8)*SD_ + ks*256 + (i & 255)];
    __syncthreads();
    const float* W = wq.p[a] + (size_t)(ks*256)*SD_ + c;
    float acc[16] = {};
    for (int i = 0; i < 256; i += 4) {
        const float w0 = W[(size_t)i*SD_];
        const float w1 = W[(size_t)(i+1)*SD_];
        const float w2 = W[(size_t)(i+2)*SD_];
        const float w3 = W[(size_t)(i+3)*SD_];
#pragma unroll
        for (int k = 0; k < 16; ++k) {
            f32x4 q4 = *(const f32x4*)&qL[k][i];
            acc[k] += q4[0]*w0 + q4[1]*w1 + q4[2]*w2 + q4[3]*w3;
        }
    }
#pragma unroll
    for (int k = 0; k < 16; ++k)
        Sp[((size_t)(a*8 + ks)*16 + k)*SD_ + c] = acc[k];
}

__global__ void qp_reduce(const float* __restrict__ Sp, Ptr5 bq, float* __restrict__ qp) {
    const int idx = blockIdx.x*256 + threadIdx.x;   // 163840
    const int a = idx >> 15, k = (idx >> 11) & 15, c = idx & 2047;
    float s = bq.p[a][c];
#pragma unroll
    for (int ks = 0; ks < 8; ++ks)
        s += Sp[((size_t)(a*8 + ks)*16 + k)*SD_ + c];
    qp[idx] = s;
}

// ============ fused scores + softmax -> P (f32) ============
__global__ __launch_bounds__(256)
void scores_sm(const u16* __restrict__ Kb, const float* __restrict__ qp,
               const int* __restrict__ units_a, float* __restrict__ P)
{
    __shared__ float sL[16][1024];
    __shared__ float qL[16][256];
    __shared__ float red[8];
    const int u = blockIdx.x >> 3, hh = blockIdx.x & 7;
    const int ua = units_a[u];
    const int t = threadIdx.x;
    for (int i = t; i < 16*256; i += 256)
        qL[i >> 8][i & 255] = qp[(size_t)(ua*16 + (i >> 8))*SD_ + hh*256 + (i & 255)];
    __syncthreads();
    const u16* Ku = Kb + (size_t)u*1024*SD_ + hh*256;
#pragma unroll
    for (int j = 0; j < 4; ++j) {
        const int n = t + j*256;
        const u16* kr = Ku + (size_t)n*SD_;
        float acc[16] = {};
        for (int d0 = 0; d0 < 256; d0 += 8) {
            u16x8 kv8 = *(const u16x8*)(kr + d0);
            float kf[8];
#pragma unroll
            for (int e = 0; e < 8; ++e) kf[e] = bf2f(kv8[e]);
#pragma unroll
            for (int k = 0; k < 16; ++k) {
                f32x4 q0 = *(const f32x4*)&qL[k][d0];
                f32x4 q1 = *(const f32x4*)&qL[k][d0+4];
                acc[k] += q0[0]*kf[0] + q0[1]*kf[1] + q0[2]*kf[2] + q0[3]*kf[3]
                        + q1[0]*kf[4] + q1[1]*kf[5] + q1[2]*kf[6] + q1[3]*kf[7];
            }
        }
#pragma unroll
        for (int k = 0; k < 16; ++k) sL[k][n] = acc[k] * 0.0625f;
    }
    __syncthreads();
    const int lane = t & 63, wv = t >> 6;
    for (int k = 0; k < 16; ++k) {
        float v0 = sL[k][t], v1 = sL[k][t+256], v2 = sL[k][t+512], v3 = sL[k][t+768];
        float mx = fmaxf(fmaxf(v0,v1), fmaxf(v2,v3));
#pragma unroll
        for (int o = 1; o < 64; o <<= 1) mx = fmaxf(mx, __shfl_xor(mx, o));
        if (lane == 0) red[wv] = mx;
        __syncthreads();
        mx = fmaxf(fmaxf(red[0],red[1]), fmaxf(red[2],red[3]));
        float e0 = expf(v0-mx), e1 = expf(v1-mx), e2 = expf(v2-mx), e3 = expf(v3-mx);
        float s = e0+e1+e2+e3;
#pragma unroll
        for (int o = 1; o < 64; o <<= 1) s += __shfl_xor(s, o);
        if (lane == 0) red[4+wv] = s;
        __syncthreads();
        s = red[4]+red[5]+red[6]+red[7];
        const float inv = 1.0f/s;
        float* Pr = P + ((size_t)(u*8+hh)*16 + k)*1024;
        Pr[t]=e0*inv; Pr[t+256]=e1*inv; Pr[t+512]=e2*inv; Pr[t+768]=e3*inv;
        __syncthreads();
    }
}

// ============ ctx: P @ V -> ctxb (bf16) ============
__global__ __launch_bounds__(256)
void ctx_u(const u16* __restrict__ Vb, const float* __restrict__ P,
           u16* __restrict__ ctxb)
{
    __shared__ float pL[16][1024];
    const int u = blockIdx.x >> 3, hh = blockIdx.x & 7;
    const int t = threadIdx.x;
    const float* Pu = P + (size_t)(u*8+hh)*16*1024;
    for (int i = t; i < 16*1024/4; i += 256)
        ((f32x4*)&pL[0][0])[i] = ((const f32x4*)Pu)[i];
    __syncthreads();
    const u16* Vu = Vb + (size_t)u*1024*SD_ + hh*256 + t;
    float acc[16] = {};
    for (int n = 0; n < 1024; n += 4) {
        float vv0 = bf2f(Vu[(size_t)n*SD_]);
        float vv1 = bf2f(Vu[(size_t)(n+1)*SD_]);
        float vv2 = bf2f(Vu[(size_t)(n+2)*SD_]);
        float vv3 = bf2f(Vu[(size_t)(n+3)*SD_]);
#pragma unroll
        for (int k = 0; k < 16; ++k) {
            f32x4 p4 = *(const f32x4*)&pL[k][n];
            acc[k] += p4[0]*vv0 + p4[1]*vv1 + p4[2]*vv2 + p4[3]*vv3;
        }
    }
#pragma unroll
    for (int k = 0; k < 16; ++k)
        ctxb[(size_t)u*16*SD_ + k*SD_ + hh*256 + t] = f2bf(acc[k]);
}

// ============ ow-GEMM ============
__global__ __launch_bounds__(256)
void gemm_ow(const u16* __restrict__ ctxb, const u16* __restrict__ Bslab,
             const float* __restrict__ biasSlab, const int* __restrict__ units_a,
             float* __restrict__ ctx2)
{
    const int u = blockIdx.y, ua = units_a[u];
    const int wave = threadIdx.x >> 6, lane = threadIdx.x & 63;
    const int col0 = blockIdx.x*256 + wave*64;
    const u16* A  = ctxb + (size_t)u*16*SD_;
    const u16* Bt = Bslab + (size_t)ua*SD_*SD_;
    const int fr = lane & 15, fk8 = (lane >> 4) << 3;
    f32x4 acc[4] = {};
    for (int k0 = 0; k0 < SD_; k0 += 32) {
        bf16x8 af = *(const bf16x8*)(A + (size_t)fr*SD_ + k0 + fk8);
#pragma unroll
        for (int n = 0; n < 4; ++n) {
            bf16x8 bf8 = *(const bf16x8*)(Bt + (size_t)(col0 + n*16 + fr)*SD_ + k0 + fk8);
            acc[n] = __builtin_amdgcn_mfma_f32_16x16x32_bf16(af, bf8, acc[n], 0, 0, 0);
        }
    }
    const int fq = lane >> 4;
#pragma unroll
    for (int n = 0; n < 4; ++n)
#pragma unroll
        for (int j = 0; j < 4; ++j) {
            const int row = fq*4 + j, col = col0 + n*16 + fr;
            ctx2[(size_t)u*16*SD_ + (size_t)row*SD_ + col] = acc[n][j] + biasSlab[ua*SD_ + col];
        }
}

// ============ final LN ============
__global__ __launch_bounds__(256)
void ln_post_u(const float* __restrict__ ctx2, const float* __restrict__ qslab,
               const float* __restrict__ pgs, const float* __restrict__ pbs,
               const int* __restrict__ units_a, const int* __restrict__ units_b,
               float* __restrict__ out, float* __restrict__ cspec)
{
    const int k = blockIdx.x, u = blockIdx.y, tid = threadIdx.x;
    const int ua = units_a[u];
    const float* ip = ctx2 + ((size_t)u*16 + k)*SD_;
    const float* qr = qslab + ((size_t)ua*16 + k)*SD_;
    const float* g  = pgs + (size_t)ua*SD_;
    const float* bt = pbs + (size_t)ua*SD_;
    float f[8]; float s = 0.f, s2 = 0.f;
#pragma unroll
    for (int j = 0; j < 8; ++j) {
        const int c = tid + j*256;
        f[j] = ip[c] + qr[c];
        s += f[j]; s2 += f[j]*f[j];
    }
    __shared__ float sa[4], sb[4];
#pragma unroll
    for (int o = 32; o > 0; o >>= 1) { s += __shfl_down(s, o); s2 += __shfl_down(s2, o); }
    if ((tid & 63) == 0) { sa[tid >> 6] = s; sb[tid >> 6] = s2; }
    __syncthreads();
    s = sa[0]+sa[1]+sa[2]+sa[3]; s2 = sb[0]+sb[1]+sb[2]+sb[3];
    const float mean = s * (1.0f/SD_);
    const float inv  = rsqrtf(s2 * (1.0f/SD_) - mean*mean + 1e-5f);
    float* op = (u < 8) ? out + ((size_t)units_b[u]*32 + k)*SD_
                        : cspec + ((size_t)(u-8)*16 + k)*SD_;
#pragma unroll
    for (int j = 0; j < 8; ++j) { const int c = tid + j*256; op[c] = (f[j]-mean)*inv*g[c] + bt[c]; }
}

// ============ router (parallel split) ============
__global__ __launch_bounds__(256)
void pool_part(const float* __restrict__ h, float* __restrict__ pp) {
    const int c = blockIdx.x*256 + threadIdx.x;
    const int b = blockIdx.y, ns = blockIdx.z;
    const float* p = h + ((size_t)b*N_ + ns*256)*TD_ + c;
    float s = 0.f;
    for (int n = 0; n < 256; ++n) s += p[(size_t)n*TD_];
    pp[(size_t)ns*8*TD_ + (size_t)b*TD_ + c] = s;
}
__global__ void pool_reduce(const float* __restrict__ pp, float* __restrict__ pooled) {
    const int idx = blockIdx.x*256 + threadIdx.x;   // 40960
    const float s = pp[idx] + pp[idx + 8*TD_] + pp[idx + 16*TD_] + pp[idx + 24*TD_];
    pooled[idx] = s * (1.0f/N_);
}

__global__ __launch_bounds__(256)
void rmlp_part(const float* __restrict__ pooled, const float* __restrict__ w1,
               float* __restrict__ rp) {
    const int c = blockIdx.x*256 + threadIdx.x;   // 0..511
    const int b = blockIdx.y, is = blockIdx.z;    // is: 10 chunks of 512
    const float* pr = pooled + b*TD_ + is*512;
    const float* W = w1 + (size_t)(is*512)*512 + c;
    float s = 0.f;
    for (int i = 0; i < 512; ++i) s += pr[i] * W[(size_t)i*512];
    rp[(b*10 + is)*512 + c] = s;
}
__global__ void rmlp_reduce(const float* __restrict__ rp, const float* __restrict__ b1,
                            float* __restrict__ hid) {
    const int idx = blockIdx.x*256 + threadIdx.x;   // 4096
    const int b = idx >> 9, c = idx & 511;
    float s = b1[c];
#pragma unroll
    for (int is = 0; is < 10; ++is) s += rp[(b*10 + is)*512 + c];
    hid[idx] = gelu_exact(s);
}

__global__ void router_final(const float* __restrict__ hid, const float* __restrict__ w2,
                             const float* __restrict__ b2, float* __restrict__ probs,
                             int* __restrict__ widx, float* __restrict__ wval,
                             int* __restrict__ units_a, int* __restrict__ units_b) {
    __shared__ float lg[8][4];
    __shared__ int sw[16];
    const int tid = threadIdx.x;
    if (tid < 32) {
        const int b = tid >> 2, m = tid & 3;
        float s = b2[m];
        const float* hr = hid + b*512;
        for (int i = 0; i < 512; ++i) s += hr[i]*w2[i*4 + m];
        lg[b][m] = s;
    }
    __syncthreads();
    if (tid < 8) {
        const int b = tid;
        const float l0=lg[b][0], l1=lg[b][1], l2=lg[b][2], l3=lg[b][3];
        const float mx = fmaxf(fmaxf(l0,l1),fmaxf(l2,l3));
        const float e0=expf(l0-mx), e1=expf(l1-mx), e2=expf(l2-mx), e3=expf(l3-mx);
        const float s = e0+e1+e2+e3;
        float p[4] = {e0/s, e1/s, e2/s, e3/s};
        probs[b*4+0]=p[0]; probs[b*4+1]=p[1]; probs[b*4+2]=p[2]; probs[b*4+3]=p[3];
        int i0 = 0;
        for (int m = 1; m < 4; ++m) if (p[m] > p[i0]) i0 = m;
        int i1 = -1;
        for (int m = 0; m < 4; ++m) if (m != i0 && (i1 < 0 || p[m] > p[i1])) i1 = m;
        const float w0 = p[i0], w1 = p[i1], ws = w0 + w1 + 1e-8f;
        widx[b*2]=i0; widx[b*2+1]=i1;
        wval[b*2]=w0/ws; wval[b*2+1]=w1/ws;
        sw[b*2]=i0; sw[b*2+1]=i1;
    }
    __syncthreads();
    if (tid < 24) {
        units_a[tid] = (tid < 8) ? 0 : sw[tid-8] + 1;
        units_b[tid] = (tid < 8) ? tid : ((tid-8) >> 1);
    }
}

__global__ void combine_k(const float* __restrict__ cspec, const int* __restrict__ widx,
                          const float* __restrict__ wval, float* __restrict__ out) {
    const int i = blockIdx.x*256 + threadIdx.x;
    const int c4 = i & 511;
    const int k  = (i >> 9) & 15;
    const int b  = i >> 13;
    const float w0 = wval[b*2], w1 = wval[b*2+1];
    const f32x4 v0 = ((const f32x4*)cspec)[(size_t)((2*b)  *16 + k)*512 + c4];
    const f32x4 v1 = ((const f32x4*)cspec)[(size_t)((2*b+1)*16 + k)*512 + c4];
    ((f32x4*)out)[(size_t)(b*32 + 16 + k)*512 + c4] = v0*w0 + v1*w1;
}

// ============ pack helpers ============
__global__ void pack5(Ptr5 src, float* __restrict__ dst, int len) {
    int i = blockIdx.x*256 + threadIdx.x;
    if (i < 5*len) dst[i] = src.p[i/len][i%len];
}
__global__ void pack_slab8(Ptr40 s, float* __restrict__ dst) {
    int i = blockIdx.x*256 + threadIdx.x;
    int slab = i / 10240, rem = i % 10240;
    dst[i] = s.p[slab][rem / 2048][rem % 2048];
}

// ============ host ============
extern "C" void kernel_launch(void* const* d_in, const int* in_sizes, int n_in,
                              void* d_out, int out_size, void* d_ws, size_t ws_size,
                              hipStream_t stream) {
    if (ws_size < 300300000ULL) return;

    const float* h = (const float*)d_in[0];
    const float* G[17]; const float* Sx[17];
    for (int i = 0; i < 17; ++i) { G[i] = (const float*)d_in[1+i]; Sx[i] = (const float*)d_in[18+i]; }
    const float* r_w1 = (const float*)d_in[35];
    const float* r_b1 = (const float*)d_in[36];
    const float* r_w2 = (const float*)d_in[37];
    const float* r_b2 = (const float*)d_in[38];

    static const size_t str[17] = {
        (size_t)TD_*BD_, BD_, (size_t)BD_*SD_, SD_, SD_, SD_, (size_t)K_*SD_,
        (size_t)SD_*SD_, (size_t)SD_*SD_, (size_t)SD_*SD_, (size_t)SD_*SD_,
        SD_, SD_, SD_, SD_, SD_, SD_ };
    auto P = [&](int pi, int a) -> const float* {
        return (a == 0) ? G[pi] : Sx[pi] + (size_t)(a-1)*str[pi];
    };

    char* w = (char*)d_ws;
    const size_t R0 = 0, R1 = 100663296, R2 = 201326592, R3 = 251658240, TAIL = 293601280;
    u16*   h_bf  = (u16*)(w + R0);
    u16*   X     = (u16*)(w + R0);
    u16*   wt_dw = (u16*)(w + R1);
    u16*   Kbuf  = (u16*)(w + R1);
    u16*   X1    = (u16*)(w + R2);
    u16*   wt_v  = (u16*)(w + R2);
    u16*   wt_ow = (u16*)(w + R2);
    u16*   wt_uw = (u16*)(w + R3);
    u16*   wt_k  = (u16*)(w + R3);
    u16*   ctxb  = (u16*)(w + R3);
    float* ctx2  = (float*)(w + R3 + 1572864);
    float* cspec = (float*)(w + R3 + 4718592);
    float* Pbuf  = (float*)(w + R3 + 6815744);
    float* qpp   = (float*)(w + R2);
    float* poolp = (float*)(w + R2 + 12582912);
    float* routp = (float*)(w + R2 + 14680064);
    float* qp_all  = (float*)(w + TAIL);
    float* qslab   = (float*)(w + TAIL + 655360);
    float* bias_dw = (float*)(w + TAIL + 1310720);
    float* slab8   = (float*)(w + TAIL + 1331200);
    float* pooled  = (float*)(w + TAIL + 1658880);
    float* hid     = (float*)(w + TAIL + 1822720);
    int*   widx    = (int*)  (w + TAIL + 1839104);
    float* wval    = (float*)(w + TAIL + 1839168);
    int*   units_a = (int*)  (w + TAIL + 1839232);
    int*   units_b = (int*)  (w + TAIL + 1839328);

    float* bias_uw = slab8;
    float* bias_k  = slab8 + 1*5*SD_;
    float* bias_v  = slab8 + 2*5*SD_;
    float* bias_ow = slab8 + 3*5*SD_;
    float* lng     = slab8 + 4*5*SD_;
    float* lnb     = slab8 + 5*5*SD_;
    float* pgs     = slab8 + 6*5*SD_;
    float* pbs     = slab8 + 7*5*SD_;

    float* out = (float*)d_out;

    // ---- conversion + router (parallel) ----
    cvt_bf16_flat<<<2048, 256, 0, stream>>>(h, h_bf, (long)((size_t)B_*N_*TD_/8));
    pool_part<<<dim3(20, 8, 4), 256, 0, stream>>>(h, poolp);
    pool_reduce<<<160, 256, 0, stream>>>(poolp, pooled);
    rmlp_part<<<dim3(2, 8, 10), 256, 0, stream>>>(pooled, r_w1, routp);
    rmlp_reduce<<<16, 256, 0, stream>>>(routp, r_b1, hid);
    router_final<<<1, 64, 0, stream>>>(hid, r_w2, r_b2, out + 524288, widx, wval, units_a, units_b);

    // ---- q projections (split-K) + packs ----
    Ptr5 q5, wq5, bq5, db5;
    for (int a = 0; a < 5; ++a) { q5.p[a]=P(6,a); wq5.p[a]=P(7,a); bq5.p[a]=P(11,a); db5.p[a]=P(1,a); }
    qp_part<<<dim3(8, 5, 8), 256, 0, stream>>>(q5, wq5, qpp);
    qp_reduce<<<640, 256, 0, stream>>>(qpp, bq5, qp_all);
    pack5<<<20, 256, 0, stream>>>(db5, bias_dw, BD_);
    pack5<<<640, 256, 0, stream>>>(q5, qslab, 16*SD_);
    Ptr40 s8;
    static const int slab_pi[8] = {3, 12, 13, 14, 4, 5, 15, 16};
    for (int si = 0; si < 8; ++si)
        for (int a = 0; a < 5; ++a) s8.p[si][a] = P(slab_pi[si], a);
    pack_slab8<<<320, 256, 0, stream>>>(s8, slab8);

    // ---- upfront transposes ----
    for (int a = 0; a < 5; ++a) {
        cvt_transpose<<<dim3(TD_/64, BD_/64), 256, 0, stream>>>(P(0,a), wt_dw + (size_t)a*BD_*TD_, TD_, BD_);
        cvt_transpose<<<dim3(BD_/64, SD_/64), 256, 0, stream>>>(P(2,a), wt_uw + (size_t)a*SD_*BD_, BD_, SD_);
    }

    // ---- down-proj (gelu): 24 units, K=5120 ----
    gemm256<1, 0><<<dim3(4, 4, 24), 512, 0, stream>>>(
        h_bf, wt_dw, (long)BD_*TD_, bias_dw, BD_, X1, BD_, (long)1024*BD_, TD_, units_a, units_b);

    // ---- up-proj: K=1024 ----
    gemm256<0, 1><<<dim3(4, 8, 24), 512, 0, stream>>>(
        X1, wt_uw, (long)SD_*BD_, bias_uw, SD_, X, SD_, (long)1024*SD_, BD_, units_a, units_b);

    // ---- LN in place ----
    ln_rows_u<<<24*1024, 256, 0, stream>>>(X, lng, lnb, units_a);

    // ---- transposes for K/V ----
    for (int a = 0; a < 5; ++a) {
        cvt_transpose<<<dim3(SD_/64, SD_/64), 256, 0, stream>>>(P(8,a), wt_k + (size_t)a*SD_*SD_, SD_, SD_);
        cvt_transpose<<<dim3(SD_/64, SD_/64), 256, 0, stream>>>(P(9,a), wt_v + (size_t)a*SD_*SD_, SD_, SD_);
    }

    // ---- K projection: K=2048 ----
    gemm256<0, 1><<<dim3(4, 8, 24), 512, 0, stream>>>(
        X, wt_k, (long)SD_*SD_, bias_k, SD_, Kbuf, SD_, (long)1024*SD_, SD_, units_a, units_b);

    // ---- scores + softmax ----
    scores_sm<<<24*8, 256, 0, stream>>>(Kbuf, qp_all, units_a, Pbuf);

    // ---- V projection ----
    gemm256<0, 1><<<dim3(4, 8, 24), 512, 0, stream>>>(
        X, wt_v, (long)SD_*SD_, bias_v, SD_, Kbuf, SD_, (long)1024*SD_, SD_, units_a, units_b);

    // ---- ow transpose ----
    for (int a = 0; a < 5; ++a)
        cvt_transpose<<<dim3(SD_/64, SD_/64), 256, 0, stream>>>(P(10,a), wt_ow + (size_t)a*SD_*SD_, SD_, SD_);

    // ---- ctx = P @ V ----
    ctx_u<<<24*8, 256, 0, stream>>>(Kbuf, Pbuf, ctxb);

    // ---- output projection ----
    gemm_ow<<<dim3(8, 24), 256, 0, stream>>>(ctxb, wt_ow, bias_ow, units_a, ctx2);

    // ---- final LN + combine ----
    ln_post_u<<<dim3(16, 24), 256, 0, stream>>>(ctx2, qslab, pgs, pbs, units_a, units_b, out, cspec);
    combine_k<<<256, 256, 0, stream>>>(cspec, widx, wval, out);
}

// Round 7
// 1360.868 us; speedup vs baseline: 2.3449x; 1.0586x over previous
//
#include <hip/hip_runtime.h>
#include <hip/hip_bf16.h>

#define B_   8
#define N_   1024
#define TD_  5120
#define SD_  2048
#define BD_  1024
#define K_   16
#define H_   8

typedef unsigned short u16;
typedef __attribute__((ext_vector_type(8))) short bf16x8;
typedef __attribute__((ext_vector_type(4))) float f32x4;
typedef __attribute__((ext_vector_type(8))) u16 u16x8;

__device__ __forceinline__ float bf2f(u16 u) {
    union { unsigned int i; float f; } x; x.i = ((unsigned)u) << 16; return x.f;
}
__device__ __forceinline__ u16 f2bf(float f) {
    union { float f; unsigned int i; } x; x.f = f;
    unsigned int i = x.i;
    return (u16)((i + 0x7fffu + ((i >> 16) & 1u)) >> 16);
}
__device__ __forceinline__ float gelu_exact(float v) {
    return 0.5f * v * (1.0f + erff(v * 0.70710678118654752f));
}
__device__ __forceinline__ void gload_lds16(const void* g, void* l) {
    __builtin_amdgcn_global_load_lds(
        (const __attribute__((address_space(1))) unsigned int*)g,
        (__attribute__((address_space(3))) unsigned int*)l, 16, 0, 0);
}

struct Ptr5 { const float* p[5]; };
struct Ptr40 { const float* p[8][5]; };

// ============ 256x256 counted-vmcnt pipelined GEMM, unit-indexed ============
// 512 threads (8 waves, 2M x 4N), BK=64, 128 KB LDS double buffer, XOR-swizzle.
// r7: 2 phases per K-tile (32 MFMA per phase, 12 ds_read_b128), 2 barriers +
// 1 vmcnt per K-tile.  Stage order: A(4 loads) .. gate .. B(4 loads).
// VM_(4) at tile start retires the current tile's 8 loads, keeps next tile's
// 4 A-loads in flight.  kk1 phase needs no gate (data gated at tile barrier).
// lgkmcnt(0) before tile-end barrier drains all reads -> next staging is safe.
template<int EPI, int AMODE>
__global__ __launch_bounds__(512, 2)
void gemm256(const u16* __restrict__ Abase,
             const u16* __restrict__ Bbase, long bStride,
             const float* __restrict__ biasBase, int biasStride,
             u16* __restrict__ Cbase, int ldc, long cStride, int Kd,
             const int* __restrict__ units_a, const int* __restrict__ units_b)
{
    __shared__ char lds[131072];
    const int u = blockIdx.z;
    const int ua = units_a[u];
    const int ub = (AMODE == 0) ? units_b[u] : u;
    const u16* A  = Abase + (size_t)ub * 1024 * Kd;
    const u16* Bt = Bbase + (size_t)ua * bStride;
    const float* bias = biasBase + (size_t)ua * biasStride;
    u16* C = Cbase + (size_t)u * cStride;

    const int tid  = threadIdx.x;
    const int wave = tid >> 6, lane = tid & 63;
    const int wm = wave >> 2, wn = wave & 3;
    const int row0 = blockIdx.x * 256, col0 = blockIdx.y * 256;

    // staging source (pre-swizzled column so linear LDS dest = swizzled layout)
    const int srow = tid >> 3;
    const int scol = ((tid & 7) ^ ((tid >> 3) & 7)) << 3;   // elems
    const char* aSrc = (const char*)(A  + (size_t)(row0 + srow) * Kd + scol);
    const char* bSrc = (const char*)(Bt + (size_t)(col0 + srow) * Kd + scol);
    const int ldsW = wave * 1024;

    const int fr = lane & 15, fq = lane >> 4;
    const int kl  = fq << 4;            // byte offset of lane's k-chunk
    const int swz = (fr & 7) << 4;

    f32x4 acc[8][4] = {};
    bf16x8 aF[8], bF[4];

#define STAGE_A(bufv, hh, kt) do { \
    const char* s_ = aSrc + ((size_t)((hh)*128) * Kd + (size_t)(kt) * 64) * 2; \
    char* d_ = lds + (bufv)*65536 + (hh)*16384 + ldsW; \
    gload_lds16(s_, d_); \
    gload_lds16(s_ + (size_t)64 * Kd * 2, d_ + 8192); } while(0)
#define STAGE_B(bufv, hh, kt) do { \
    const char* s_ = bSrc + ((size_t)((hh)*128) * Kd + (size_t)(kt) * 64) * 2; \
    char* d_ = lds + (bufv)*65536 + 32768 + (hh)*16384 + ldsW; \
    gload_lds16(s_, d_); \
    gload_lds16(s_ + (size_t)64 * Kd * 2, d_ + 8192); } while(0)

#define LDA_(bufv, mf, kk) (*(const bf16x8*)(lds + (bufv)*65536 + \
    ((mf)*32 + wm*16 + fr)*128 + ((((kk)*64) + kl) ^ swz)))
#define LDB_(bufv, nf, kk) (*(const bf16x8*)(lds + (bufv)*65536 + 32768 + \
    (wn*64 + (nf)*16 + fr)*128 + ((((kk)*64) + kl) ^ swz)))

#define FENCE_ asm volatile("" ::: "memory")
#define BAR_   __builtin_amdgcn_s_barrier()
#define WAITL_ asm volatile("s_waitcnt lgkmcnt(0)" ::: "memory")
#define VM_(n) asm volatile("s_waitcnt vmcnt(" #n ")" ::: "memory")

#define READ_B(bufv, kk) { _Pragma("unroll") \
    for (int n_ = 0; n_ < 4; ++n_) bF[n_] = LDB_(bufv, n_, kk); }
#define READ_A8(bufv, kk) { _Pragma("unroll") \
    for (int i_ = 0; i_ < 8; ++i_) aF[i_] = LDA_(bufv, i_, kk); }
#define MFMA32_ { __builtin_amdgcn_s_setprio(1); \
    _Pragma("unroll") for (int i_ = 0; i_ < 8; ++i_) { \
      _Pragma("unroll") for (int n_ = 0; n_ < 4; ++n_) \
        acc[i_][n_] = __builtin_amdgcn_mfma_f32_16x16x32_bf16( \
            aF[i_], bF[n_], acc[i_][n_], 0, 0, 0); } \
    __builtin_amdgcn_s_setprio(0); }

    // prologue: tile 0 -> buf0 (order: A0,A1,B0,B1 = 8 loads)
    STAGE_A(0, 0, 0); STAGE_A(0, 1, 0);
    STAGE_B(0, 0, 0); STAGE_B(0, 1, 0);

    const int nt = Kd >> 6;
    for (int T = 0; T < nt - 1; ++T) {
        const int bufv = T & 1, nb = bufv ^ 1;
        // stage next tile's A halves (4 loads)
        STAGE_A(nb, 0, T + 1); STAGE_A(nb, 1, T + 1);
        // gate: retire current tile's 8 loads; keep next tile's 4 A-loads
        VM_(4); BAR_; FENCE_;
        // phase kk0: 12 reads, 32 MFMA; stage next tile's B mid-phase
        READ_B(bufv, 0); READ_A8(bufv, 0);
        STAGE_B(nb, 0, T + 1); STAGE_B(nb, 1, T + 1);
        WAITL_; MFMA32_;
        // phase kk1 (gated at this tile's barrier)
        READ_B(bufv, 1); READ_A8(bufv, 1);
        WAITL_; MFMA32_;
        BAR_;   // tile end: all reads drained (WAITL above) -> staging safe
    }
    {
        const int bufv = (nt - 1) & 1;
        VM_(0); BAR_; FENCE_;
        READ_B(bufv, 0); READ_A8(bufv, 0);
        WAITL_; MFMA32_;
        READ_B(bufv, 1); READ_A8(bufv, 1);
        WAITL_; MFMA32_;
    }

#undef STAGE_A
#undef STAGE_B
#undef LDA_
#undef LDB_
#undef FENCE_
#undef BAR_
#undef WAITL_
#undef VM_
#undef READ_B
#undef READ_A8
#undef MFMA32_

#pragma unroll
    for (int mf = 0; mf < 8; ++mf)
#pragma unroll
        for (int nf = 0; nf < 4; ++nf) {
            const int col = col0 + wn*64 + nf*16 + fr;
            const float bv = bias[col];
#pragma unroll
            for (int j = 0; j < 4; ++j) {
                const int row = row0 + mf*32 + wm*16 + fq*4 + j;
                float v = acc[mf][nf][j] + bv;
                if (EPI == 1) v = gelu_exact(v);
                C[(size_t)row*ldc + col] = f2bf(v);
            }
        }
}

// ============ conversions ============
__global__ void cvt_bf16_flat(const float* __restrict__ in, u16* __restrict__ out, long n8) {
    long i = (long)blockIdx.x * blockDim.x + threadIdx.x;
    const long stride = (long)gridDim.x * blockDim.x;
    for (; i < n8; i += stride) {
        const f32x4* p = (const f32x4*)in + i*2;
        f32x4 a = p[0], b = p[1];
        u16x8 o;
        o[0]=f2bf(a[0]); o[1]=f2bf(a[1]); o[2]=f2bf(a[2]); o[3]=f2bf(a[3]);
        o[4]=f2bf(b[0]); o[5]=f2bf(b[1]); o[6]=f2bf(b[2]); o[7]=f2bf(b[3]);
        ((u16x8*)out)[i] = o;
    }
}

__global__ __launch_bounds__(256)
void cvt_transpose(const float* __restrict__ W, u16* __restrict__ Wt, int Kd, int Nd) {
    __shared__ float t[64][65];
    const int k0 = blockIdx.x * 64, n0 = blockIdx.y * 64;
    const int tid = threadIdx.x;
#pragma unroll
    for (int i = 0; i < 4; ++i) {
        int ch = tid + i*256;
        int r = ch >> 4, c4 = (ch & 15) << 2;
        f32x4 v = *(const f32x4*)(W + (size_t)(k0 + r)*Nd + n0 + c4);
        t[r][c4] = v[0]; t[r][c4+1] = v[1]; t[r][c4+2] = v[2]; t[r][c4+3] = v[3];
    }
    __syncthreads();
#pragma unroll
    for (int i = 0; i < 2; ++i) {
        int ch = tid + i*256;
        int nr = ch >> 3, c8 = (ch & 7) << 3;
        u16x8 o;
#pragma unroll
        for (int j = 0; j < 8; ++j) o[j] = f2bf(t[c8 + j][nr]);
        *(u16x8*)(Wt + (size_t)(n0 + nr)*Kd + k0 + c8) = o;
    }
}

// ============ LayerNorm in place (bf16), unit-indexed params ============
__global__ __launch_bounds__(256)
void ln_rows_u(u16* __restrict__ X, const float* __restrict__ gslab,
               const float* __restrict__ bslab, const int* __restrict__ units_a) {
    const int row = blockIdx.x, tid = threadIdx.x;
    const int ua = units_a[row >> 10];
    const float* g  = gslab + (size_t)ua*SD_;
    const float* bt = bslab + (size_t)ua*SD_;
    u16* rp = X + (size_t)row*SD_;
    const u16x8 v = ((const u16x8*)rp)[tid];
    float f[8]; float s = 0.f, s2 = 0.f;
#pragma unroll
    for (int j = 0; j < 8; ++j) { f[j] = bf2f(v[j]); s += f[j]; s2 += f[j]*f[j]; }
    __shared__ float sa[4], sb[4];
#pragma unroll
    for (int o = 32; o > 0; o >>= 1) { s += __shfl_down(s, o); s2 += __shfl_down(s2, o); }
    if ((tid & 63) == 0) { sa[tid >> 6] = s; sb[tid >> 6] = s2; }
    __syncthreads();
    s = sa[0]+sa[1]+sa[2]+sa[3]; s2 = sb[0]+sb[1]+sb[2]+sb[3];
    const float mean = s * (1.0f/SD_);
    const float inv  = rsqrtf(s2 * (1.0f/SD_) - mean*mean + 1e-5f);
    const int c0 = tid*8;
    u16x8 o;
#pragma unroll
    for (int j = 0; j < 8; ++j) o[j] = f2bf((f[j]-mean)*inv*g[c0+j] + bt[c0+j]);
    ((u16x8*)rp)[tid] = o;
}

// ============ q-projection: split-K parallel ============
__global__ __launch_bounds__(256)
void qp_part(Ptr5 q, Ptr5 wq, float* __restrict__ Sp) {
    __shared__ float qL[16][256];
    const int a = blockIdx.y, ks = blockIdx.z;
    const int c = blockIdx.x*256 + threadIdx.x;
    const int t = threadIdx.x;
    const float* Q = q.p[a];
    for (int i = t; i < 16*256; i += 256)
        qL[i >> 8][i & 255] = Q[(size_t)(i >> 8)*SD_ + ks*256 + (i & 255)];
    __syncthreads();
    const float* W = wq.p[a] + (size_t)(ks*256)*SD_ + c;
    float acc[16] = {};
    for (int i = 0; i < 256; i += 4) {
        const float w0 = W[(size_t)i*SD_];
        const float w1 = W[(size_t)(i+1)*SD_];
        const float w2 = W[(size_t)(i+2)*SD_];
        const float w3 = W[(size_t)(i+3)*SD_];
#pragma unroll
        for (int k = 0; k < 16; ++k) {
            f32x4 q4 = *(const f32x4*)&qL[k][i];
            acc[k] += q4[0]*w0 + q4[1]*w1 + q4[2]*w2 + q4[3]*w3;
        }
    }
#pragma unroll
    for (int k = 0; k < 16; ++k)
        Sp[((size_t)(a*8 + ks)*16 + k)*SD_ + c] = acc[k];
}

__global__ void qp_reduce(const float* __restrict__ Sp, Ptr5 bq, float* __restrict__ qp) {
    const int idx = blockIdx.x*256 + threadIdx.x;   // 163840
    const int a = idx >> 15, k = (idx >> 11) & 15, c = idx & 2047;
    float s = bq.p[a][c];
#pragma unroll
    for (int ks = 0; ks < 8; ++ks)
        s += Sp[((size_t)(a*8 + ks)*16 + k)*SD_ + c];
    qp[idx] = s;
}

// ============ fused scores + softmax -> P (f32) ============
__global__ __launch_bounds__(256)
void scores_sm(const u16* __restrict__ Kb, const float* __restrict__ qp,
               const int* __restrict__ units_a, float* __restrict__ P)
{
    __shared__ float sL[16][1024];
    __shared__ float qL[16][256];
    __shared__ float red[8];
    const int u = blockIdx.x >> 3, hh = blockIdx.x & 7;
    const int ua = units_a[u];
    const int t = threadIdx.x;
    for (int i = t; i < 16*256; i += 256)
        qL[i >> 8][i & 255] = qp[(size_t)(ua*16 + (i >> 8))*SD_ + hh*256 + (i & 255)];
    __syncthreads();
    const u16* Ku = Kb + (size_t)u*1024*SD_ + hh*256;
#pragma unroll
    for (int j = 0; j < 4; ++j) {
        const int n = t + j*256;
        const u16* kr = Ku + (size_t)n*SD_;
        float acc[16] = {};
        for (int d0 = 0; d0 < 256; d0 += 8) {
            u16x8 kv8 = *(const u16x8*)(kr + d0);
            float kf[8];
#pragma unroll
            for (int e = 0; e < 8; ++e) kf[e] = bf2f(kv8[e]);
#pragma unroll
            for (int k = 0; k < 16; ++k) {
                f32x4 q0 = *(const f32x4*)&qL[k][d0];
                f32x4 q1 = *(const f32x4*)&qL[k][d0+4];
                acc[k] += q0[0]*kf[0] + q0[1]*kf[1] + q0[2]*kf[2] + q0[3]*kf[3]
                        + q1[0]*kf[4] + q1[1]*kf[5] + q1[2]*kf[6] + q1[7==7?7:7]*kf[7];
            }
        }
#pragma unroll
        for (int k = 0; k < 16; ++k) sL[k][n] = acc[k] * 0.0625f;
    }
    __syncthreads();
    const int lane = t & 63, wv = t >> 6;
    for (int k = 0; k < 16; ++k) {
        float v0 = sL[k][t], v1 = sL[k][t+256], v2 = sL[k][t+512], v3 = sL[k][t+768];
        float mx = fmaxf(fmaxf(v0,v1), fmaxf(v2,v3));
#pragma unroll
        for (int o = 1; o < 64; o <<= 1) mx = fmaxf(mx, __shfl_xor(mx, o));
        if (lane == 0) red[wv] = mx;
        __syncthreads();
        mx = fmaxf(fmaxf(red[0],red[1]), fmaxf(red[2],red[3]));
        float e0 = expf(v0-mx), e1 = expf(v1-mx), e2 = expf(v2-mx), e3 = expf(v3-mx);
        float s = e0+e1+e2+e3;
#pragma unroll
        for (int o = 1; o < 64; o <<= 1) s += __shfl_xor(s, o);
        if (lane == 0) red[4+wv] = s;
        __syncthreads();
        s = red[4]+red[5]+red[6]+red[7];
        const float inv = 1.0f/s;
        float* Pr = P + ((size_t)(u*8+hh)*16 + k)*1024;
        Pr[t]=e0*inv; Pr[t+256]=e1*inv; Pr[t+512]=e2*inv; Pr[t+768]=e3*inv;
        __syncthreads();
    }
}

// ============ ctx: P @ V -> ctxb (bf16) ============
__global__ __launch_bounds__(256)
void ctx_u(const u16* __restrict__ Vb, const float* __restrict__ P,
           u16* __restrict__ ctxb)
{
    __shared__ float pL[16][1024];
    const int u = blockIdx.x >> 3, hh = blockIdx.x & 7;
    const int t = threadIdx.x;
    const float* Pu = P + (size_t)(u*8+hh)*16*1024;
    for (int i = t; i < 16*1024/4; i += 256)
        ((f32x4*)&pL[0][0])[i] = ((const f32x4*)Pu)[i];
    __syncthreads();
    const u16* Vu = Vb + (size_t)u*1024*SD_ + hh*256 + t;
    float acc[16] = {};
    for (int n = 0; n < 1024; n += 4) {
        float vv0 = bf2f(Vu[(size_t)n*SD_]);
        float vv1 = bf2f(Vu[(size_t)(n+1)*SD_]);
        float vv2 = bf2f(Vu[(size_t)(n+2)*SD_]);
        float vv3 = bf2f(Vu[(size_t)(n+3)*SD_]);
#pragma unroll
        for (int k = 0; k < 16; ++k) {
            f32x4 p4 = *(const f32x4*)&pL[k][n];
            acc[k] += p4[0]*vv0 + p4[1]*vv1 + p4[2]*vv2 + p4[3]*vv3;
        }
    }
#pragma unroll
    for (int k = 0; k < 16; ++k)
        ctxb[(size_t)u*16*SD_ + k*SD_ + hh*256 + t] = f2bf(acc[k]);
}

// ============ ow-GEMM ============
__global__ __launch_bounds__(256)
void gemm_ow(const u16* __restrict__ ctxb, const u16* __restrict__ Bslab,
             const float* __restrict__ biasSlab, const int* __restrict__ units_a,
             float* __restrict__ ctx2)
{
    const int u = blockIdx.y, ua = units_a[u];
    const int wave = threadIdx.x >> 6, lane = threadIdx.x & 63;
    const int col0 = blockIdx.x*256 + wave*64;
    const u16* A  = ctxb + (size_t)u*16*SD_;
    const u16* Bt = Bslab + (size_t)ua*SD_*SD_;
    const int fr = lane & 15, fk8 = (lane >> 4) << 3;
    f32x4 acc[4] = {};
    for (int k0 = 0; k0 < SD_; k0 += 32) {
        bf16x8 af = *(const bf16x8*)(A + (size_t)fr*SD_ + k0 + fk8);
#pragma unroll
        for (int n = 0; n < 4; ++n) {
            bf16x8 bf8 = *(const bf16x8*)(Bt + (size_t)(col0 + n*16 + fr)*SD_ + k0 + fk8);
            acc[n] = __builtin_amdgcn_mfma_f32_16x16x32_bf16(af, bf8, acc[n], 0, 0, 0);
        }
    }
    const int fq = lane >> 4;
#pragma unroll
    for (int n = 0; n < 4; ++n)
#pragma unroll
        for (int j = 0; j < 4; ++j) {
            const int row = fq*4 + j, col = col0 + n*16 + fr;
            ctx2[(size_t)u*16*SD_ + (size_t)row*SD_ + col] = acc[n][j] + biasSlab[ua*SD_ + col];
        }
}

// ============ final LN ============
__global__ __launch_bounds__(256)
void ln_post_u(const float* __restrict__ ctx2, const float* __restrict__ qslab,
               const float* __restrict__ pgs, const float* __restrict__ pbs,
               const int* __restrict__ units_a, const int* __restrict__ units_b,
               float* __restrict__ out, float* __restrict__ cspec)
{
    const int k = blockIdx.x, u = blockIdx.y, tid = threadIdx.x;
    const int ua = units_a[u];
    const float* ip = ctx2 + ((size_t)u*16 + k)*SD_;
    const float* qr = qslab + ((size_t)ua*16 + k)*SD_;
    const float* g  = pgs + (size_t)ua*SD_;
    const float* bt = pbs + (size_t)ua*SD_;
    float f[8]; float s = 0.f, s2 = 0.f;
#pragma unroll
    for (int j = 0; j < 8; ++j) {
        const int c = tid + j*256;
        f[j] = ip[c] + qr[c];
        s += f[j]; s2 += f[j]*f[j];
    }
    __shared__ float sa[4], sb[4];
#pragma unroll
    for (int o = 32; o > 0; o >>= 1) { s += __shfl_down(s, o); s2 += __shfl_down(s2, o); }
    if ((tid & 63) == 0) { sa[tid >> 6] = s; sb[tid >> 6] = s2; }
    __syncthreads();
    s = sa[0]+sa[1]+sa[2]+sa[3]; s2 = sb[0]+sb[1]+sb[2]+sb[3];
    const float mean = s * (1.0f/SD_);
    const float inv  = rsqrtf(s2 * (1.0f/SD_) - mean*mean + 1e-5f);
    float* op = (u < 8) ? out + ((size_t)units_b[u]*32 + k)*SD_
                        : cspec + ((size_t)(u-8)*16 + k)*SD_;
#pragma unroll
    for (int j = 0; j < 8; ++j) { const int c = tid + j*256; op[c] = (f[j]-mean)*inv*g[c] + bt[c]; }
}

// ============ router (parallel split) ============
__global__ __launch_bounds__(256)
void pool_part(const float* __restrict__ h, float* __restrict__ pp) {
    const int c = blockIdx.x*256 + threadIdx.x;
    const int b = blockIdx.y, ns = blockIdx.z;
    const float* p = h + ((size_t)b*N_ + ns*256)*TD_ + c;
    float s = 0.f;
    for (int n = 0; n < 256; ++n) s += p[(size_t)n*TD_];
    pp[(size_t)ns*8*TD_ + (size_t)b*TD_ + c] = s;
}
__global__ void pool_reduce(const float* __restrict__ pp, float* __restrict__ pooled) {
    const int idx = blockIdx.x*256 + threadIdx.x;   // 40960
    const float s = pp[idx] + pp[idx + 8*TD_] + pp[idx + 16*TD_] + pp[idx + 24*TD_];
    pooled[idx] = s * (1.0f/N_);
}

__global__ __launch_bounds__(256)
void rmlp_part(const float* __restrict__ pooled, const float* __restrict__ w1,
               float* __restrict__ rp) {
    const int c = blockIdx.x*256 + threadIdx.x;   // 0..511
    const int b = blockIdx.y, is = blockIdx.z;    // is: 10 chunks of 512
    const float* pr = pooled + b*TD_ + is*512;
    const float* W = w1 + (size_t)(is*512)*512 + c;
    float s = 0.f;
    for (int i = 0; i < 512; ++i) s += pr[i] * W[(size_t)i*512];
    rp[(b*10 + is)*512 + c] = s;
}
__global__ void rmlp_reduce(const float* __restrict__ rp, const float* __restrict__ b1,
                            float* __restrict__ hid) {
    const int idx = blockIdx.x*256 + threadIdx.x;   // 4096
    const int b = idx >> 9, c = idx & 511;
    float s = b1[c];
#pragma unroll
    for (int is = 0; is < 10; ++is) s += rp[(b*10 + is)*512 + c];
    hid[idx] = gelu_exact(s);
}

__global__ void router_final(const float* __restrict__ hid, const float* __restrict__ w2,
                             const float* __restrict__ b2, float* __restrict__ probs,
                             int* __restrict__ widx, float* __restrict__ wval,
                             int* __restrict__ units_a, int* __restrict__ units_b) {
    __shared__ float lg[8][4];
    __shared__ int sw[16];
    const int tid = threadIdx.x;
    if (tid < 32) {
        const int b = tid >> 2, m = tid & 3;
        float s = b2[m];
        const float* hr = hid + b*512;
        for (int i = 0; i < 512; ++i) s += hr[i]*w2[i*4 + m];
        lg[b][m] = s;
    }
    __syncthreads();
    if (tid < 8) {
        const int b = tid;
        const float l0=lg[b][0], l1=lg[b][1], l2=lg[b][2], l3=lg[b][3];
        const float mx = fmaxf(fmaxf(l0,l1),fmaxf(l2,l3));
        const float e0=expf(l0-mx), e1=expf(l1-mx), e2=expf(l2-mx), e3=expf(l3-mx);
        const float s = e0+e1+e2+e3;
        float p[4] = {e0/s, e1/s, e2/s, e3/s};
        probs[b*4+0]=p[0]; probs[b*4+1]=p[1]; probs[b*4+2]=p[2]; probs[b*4+3]=p[3];
        int i0 = 0;
        for (int m = 1; m < 4; ++m) if (p[m] > p[i0]) i0 = m;
        int i1 = -1;
        for (int m = 0; m < 4; ++m) if (m != i0 && (i1 < 0 || p[m] > p[i1])) i1 = m;
        const float w0 = p[i0], w1 = p[i1], ws = w0 + w1 + 1e-8f;
        widx[b*2]=i0; widx[b*2+1]=i1;
        wval[b*2]=w0/ws; wval[b*2+1]=w1/ws;
        sw[b*2]=i0; sw[b*2+1]=i1;
    }
    __syncthreads();
    if (tid < 24) {
        units_a[tid] = (tid < 8) ? 0 : sw[tid-8] + 1;
        units_b[tid] = (tid < 8) ? tid : ((tid-8) >> 1);
    }
}

__global__ void combine_k(const float* __restrict__ cspec, const int* __restrict__ widx,
                          const float* __restrict__ wval, float* __restrict__ out) {
    const int i = blockIdx.x*256 + threadIdx.x;
    const int c4 = i & 511;
    const int k  = (i >> 9) & 15;
    const int b  = i >> 13;
    const float w0 = wval[b*2], w1 = wval[b*2+1];
    const f32x4 v0 = ((const f32x4*)cspec)[(size_t)((2*b)  *16 + k)*512 + c4];
    const f32x4 v1 = ((const f32x4*)cspec)[(size_t)((2*b+1)*16 + k)*512 + c4];
    ((f32x4*)out)[(size_t)(b*32 + 16 + k)*512 + c4] = v0*w0 + v1*w1;
}

// ============ pack helpers ============
__global__ void pack5(Ptr5 src, float* __restrict__ dst, int len) {
    int i = blockIdx.x*256 + threadIdx.x;
    if (i < 5*len) dst[i] = src.p[i/len][i%len];
}
__global__ void pack_slab8(Ptr40 s, float* __restrict__ dst) {
    int i = blockIdx.x*256 + threadIdx.x;
    int slab = i / 10240, rem = i % 10240;
    dst[i] = s.p[slab][rem / 2048][rem % 2048];
}

// ============ host ============
extern "C" void kernel_launch(void* const* d_in, const int* in_sizes, int n_in,
                              void* d_out, int out_size, void* d_ws, size_t ws_size,
                              hipStream_t stream) {
    if (ws_size < 300300000ULL) return;

    const float* h = (const float*)d_in[0];
    const float* G[17]; const float* Sx[17];
    for (int i = 0; i < 17; ++i) { G[i] = (const float*)d_in[1+i]; Sx[i] = (const float*)d_in[18+i]; }
    const float* r_w1 = (const float*)d_in[35];
    const float* r_b1 = (const float*)d_in[36];
    const float* r_w2 = (const float*)d_in[37];
    const float* r_b2 = (const float*)d_in[38];

    static const size_t str[17] = {
        (size_t)TD_*BD_, BD_, (size_t)BD_*SD_, SD_, SD_, SD_, (size_t)K_*SD_,
        (size_t)SD_*SD_, (size_t)SD_*SD_, (size_t)SD_*SD_, (size_t)SD_*SD_,
        SD_, SD_, SD_, SD_, SD_, SD_ };
    auto P = [&](int pi, int a) -> const float* {
        return (a == 0) ? G[pi] : Sx[pi] + (size_t)(a-1)*str[pi];
    };

    char* w = (char*)d_ws;
    const size_t R0 = 0, R1 = 100663296, R2 = 201326592, R3 = 251658240, TAIL = 293601280;
    u16*   h_bf  = (u16*)(w + R0);
    u16*   X     = (u16*)(w + R0);
    u16*   wt_dw = (u16*)(w + R1);
    u16*   Kbuf  = (u16*)(w + R1);
    u16*   X1    = (u16*)(w + R2);
    u16*   wt_v  = (u16*)(w + R2);
    u16*   wt_ow = (u16*)(w + R2);
    u16*   wt_uw = (u16*)(w + R3);
    u16*   wt_k  = (u16*)(w + R3);
    u16*   ctxb  = (u16*)(w + R3);
    float* ctx2  = (float*)(w + R3 + 1572864);
    float* cspec = (float*)(w + R3 + 4718592);
    float* Pbuf  = (float*)(w + R3 + 6815744);
    float* qpp   = (float*)(w + R2);
    float* poolp = (float*)(w + R2 + 12582912);
    float* routp = (float*)(w + R2 + 14680064);
    float* qp_all  = (float*)(w + TAIL);
    float* qslab   = (float*)(w + TAIL + 655360);
    float* bias_dw = (float*)(w + TAIL + 1310720);
    float* slab8   = (float*)(w + TAIL + 1331200);
    float* pooled  = (float*)(w + TAIL + 1658880);
    float* hid     = (float*)(w + TAIL + 1822720);
    int*   widx    = (int*)  (w + TAIL + 1839104);
    float* wval    = (float*)(w + TAIL + 1839168);
    int*   units_a = (int*)  (w + TAIL + 1839232);
    int*   units_b = (int*)  (w + TAIL + 1839328);

    float* bias_uw = slab8;
    float* bias_k  = slab8 + 1*5*SD_;
    float* bias_v  = slab8 + 2*5*SD_;
    float* bias_ow = slab8 + 3*5*SD_;
    float* lng     = slab8 + 4*5*SD_;
    float* lnb     = slab8 + 5*5*SD_;
    float* pgs     = slab8 + 6*5*SD_;
    float* pbs     = slab8 + 7*5*SD_;

    float* out = (float*)d_out;

    // ---- conversion + router (parallel) ----
    cvt_bf16_flat<<<2048, 256, 0, stream>>>(h, h_bf, (long)((size_t)B_*N_*TD_/8));
    pool_part<<<dim3(20, 8, 4), 256, 0, stream>>>(h, poolp);
    pool_reduce<<<160, 256, 0, stream>>>(poolp, pooled);
    rmlp_part<<<dim3(2, 8, 10), 256, 0, stream>>>(pooled, r_w1, routp);
    rmlp_reduce<<<16, 256, 0, stream>>>(routp, r_b1, hid);
    router_final<<<1, 64, 0, stream>>>(hid, r_w2, r_b2, out + 524288, widx, wval, units_a, units_b);

    // ---- q projections (split-K) + packs ----
    Ptr5 q5, wq5, bq5, db5;
    for (int a = 0; a < 5; ++a) { q5.p[a]=P(6,a); wq5.p[a]=P(7,a); bq5.p[a]=P(11,a); db5.p[a]=P(1,a); }
    qp_part<<<dim3(8, 5, 8), 256, 0, stream>>>(q5, wq5, qpp);
    qp_reduce<<<640, 256, 0, stream>>>(qpp, bq5, qp_all);
    pack5<<<20, 256, 0, stream>>>(db5, bias_dw, BD_);
    pack5<<<640, 256, 0, stream>>>(q5, qslab, 16*SD_);
    Ptr40 s8;
    static const int slab_pi[8] = {3, 12, 13, 14, 4, 5, 15, 16};
    for (int si = 0; si < 8; ++si)
        for (int a = 0; a < 5; ++a) s8.p[si][a] = P(slab_pi[si], a);
    pack_slab8<<<320, 256, 0, stream>>>(s8, slab8);

    // ---- upfront transposes ----
    for (int a = 0; a < 5; ++a) {
        cvt_transpose<<<dim3(TD_/64, BD_/64), 256, 0, stream>>>(P(0,a), wt_dw + (size_t)a*BD_*TD_, TD_, BD_);
        cvt_transpose<<<dim3(BD_/64, SD_/64), 256, 0, stream>>>(P(2,a), wt_uw + (size_t)a*SD_*BD_, BD_, SD_);
    }

    // ---- down-proj (gelu): 24 units, K=5120 ----
    gemm256<1, 0><<<dim3(4, 4, 24), 512, 0, stream>>>(
        h_bf, wt_dw, (long)BD_*TD_, bias_dw, BD_, X1, BD_, (long)1024*BD_, TD_, units_a, units_b);

    // ---- up-proj: K=1024 ----
    gemm256<0, 1><<<dim3(4, 8, 24), 512, 0, stream>>>(
        X1, wt_uw, (long)SD_*BD_, bias_uw, SD_, X, SD_, (long)1024*SD_, BD_, units_a, units_b);

    // ---- LN in place ----
    ln_rows_u<<<24*1024, 256, 0, stream>>>(X, lng, lnb, units_a);

    // ---- transposes for K/V ----
    for (int a = 0; a < 5; ++a) {
        cvt_transpose<<<dim3(SD_/64, SD_/64), 256, 0, stream>>>(P(8,a), wt_k + (size_t)a*SD_*SD_, SD_, SD_);
        cvt_transpose<<<dim3(SD_/64, SD_/64), 256, 0, stream>>>(P(9,a), wt_v + (size_t)a*SD_*SD_, SD_, SD_);
    }

    // ---- K projection: K=2048 ----
    gemm256<0, 1><<<dim3(4, 8, 24), 512, 0, stream>>>(
        X, wt_k, (long)SD_*SD_, bias_k, SD_, Kbuf, SD_, (long)1024*SD_, SD_, units_a, units_b);

    // ---- scores + softmax ----
    scores_sm<<<24*8, 256, 0, stream>>>(Kbuf, qp_all, units_a, Pbuf);

    // ---- V projection ----
    gemm256<0, 1><<<dim3(4, 8, 24), 512, 0, stream>>>(
        X, wt_v, (long)SD_*SD_, bias_v, SD_, Kbuf, SD_, (long)1024*SD_, SD_, units_a, units_b);

    // ---- ow transpose ----
    for (int a = 0; a < 5; ++a)
        cvt_transpose<<<dim3(SD_/64, SD_/64), 256, 0, stream>>>(P(10,a), wt_ow + (size_t)a*SD_*SD_, SD_, SD_);

    // ---- ctx = P @ V ----
    ctx_u<<<24*8, 256, 0, stream>>>(Kbuf, Pbuf, ctxb);

    // ---- output projection ----
    gemm_ow<<<dim3(8, 24), 256, 0, stream>>>(ctxb, wt_ow, bias_ow, units_a, ctx2);

    // ---- final LN + combine ----
    ln_post_u<<<dim3(16, 24), 256, 0, stream>>>(ctx2, qslab, pgs, pbs, units_a, units_b, out, cspec);
    combine_k<<<256, 256, 0, stream>>>(cspec, widx, wval, out);
}